// Round 1
// baseline (553.238 us; speedup 1.0000x reference)
//
#include <hip/hip_runtime.h>

#define N_ROWS 8192
#define D_DIM  1024

typedef _Float16 f16;
typedef _Float16 f16x8 __attribute__((ext_vector_type(8)));
typedef _Float16 f16x4 __attribute__((ext_vector_type(4)));
typedef float    f32x4 __attribute__((ext_vector_type(4)));

__device__ inline void gload_lds16(const void* g, void* l) {
  __builtin_amdgcn_global_load_lds(
      (const __attribute__((address_space(1))) void*)g,
      (__attribute__((address_space(3))) void*)l, 16, 0, 0);
}

// ---------------------------------------------------------------- converts
__global__ __launch_bounds__(256) void f32_to_f16_kernel(
    const float* __restrict__ in, f16* __restrict__ out, int n4) {
  for (int i = blockIdx.x * blockDim.x + threadIdx.x; i < n4;
       i += gridDim.x * blockDim.x) {
    float4 x = ((const float4*)in)[i];
    f16x4 h = {(f16)x.x, (f16)x.y, (f16)x.z, (f16)x.w};
    ((f16x4*)out)[i] = h;
  }
}

__global__ __launch_bounds__(256) void transpose_w_kernel(
    const float* __restrict__ w0, const float* __restrict__ w1,
    const float* __restrict__ w2, f16* __restrict__ WT) {
  const float* W = (blockIdx.z == 0) ? w0 : (blockIdx.z == 1) ? w1 : w2;
  f16* T = WT + (size_t)blockIdx.z * D_DIM * D_DIM;
  __shared__ float tile[64][65];
  const int r0 = blockIdx.y * 64, c0 = blockIdx.x * 64;
  const int t = threadIdx.x;
#pragma unroll
  for (int rep = 0; rep < 16; ++rep) {
    int idx = rep * 256 + t;
    int r = idx >> 6, c = idx & 63;
    tile[r][c] = W[(size_t)(r0 + r) * D_DIM + (c0 + c)];
  }
  __syncthreads();
#pragma unroll
  for (int rep = 0; rep < 16; ++rep) {
    int idx = rep * 256 + t;
    int r = idx >> 6, c = idx & 63;
    T[(size_t)(c0 + r) * D_DIM + (r0 + c)] = (f16)tile[c][r];
  }
}

// ---------------------------------------------------------------- GEMM
// C[M x N] = A[M x K] * B[K x N], with B supplied TRANSPOSED (BT[N x K]).
// MODE 0: store f16 C ; MODE 1: store f16 C transposed (CT[N x M], ldc = CT
// row stride) ; MODE 2: store fp32 C.  scale applied to acc before store.
// Tile 128x128, BK=32, 4 waves (2x2), 16x16x32 f16 MFMA, double-buffered LDS
// staged via global_load_lds width=16 (m97 structure).
template <int MODE>
__global__ __launch_bounds__(256) void gemm_tn(
    const f16* __restrict__ A, int lda, const f16* __restrict__ BT, int ldbt,
    void* __restrict__ C, int ldc, int K, float scale) {
  __shared__ f16 As[2][128 * 32];
  __shared__ f16 Bs[2][128 * 32];
  const int tid = threadIdx.x;
  const int lane = tid & 63;
  const int w = tid >> 6;
  const int wr = w >> 1, wc = w & 1;
  const int m0 = blockIdx.y * 128, n0 = blockIdx.x * 128;

  const f16* Abase = A + (size_t)m0 * lda;
  const f16* Bbase = BT + (size_t)n0 * ldbt;

  auto stage = [&](int buf, int kt) {
    const int k0 = kt * 32;
#pragma unroll
    for (int c = 0; c < 2; ++c) {
      const int q = c * 256 + tid;       // 512 x 16B chunks per 8KB tile
      const int row = q >> 2;            // tile row (64B per row)
      const int col = (q & 3) * 8;       // element offset within row
      gload_lds16(Abase + (size_t)row * lda + (k0 + col), &As[buf][q * 8]);
      gload_lds16(Bbase + (size_t)row * ldbt + (k0 + col), &Bs[buf][q * 8]);
    }
  };

  f32x4 acc[4][4];
#pragma unroll
  for (int i = 0; i < 4; ++i)
#pragma unroll
    for (int j = 0; j < 4; ++j) acc[i][j] = (f32x4){0.f, 0.f, 0.f, 0.f};

  stage(0, 0);
  const int nk = K >> 5;
  const int ro = lane & 15;
  const int ko = (lane >> 4) * 8;

  for (int kt = 0; kt < nk; ++kt) {
    const int buf = kt & 1;
    __syncthreads();  // drains vmcnt -> buf ready; protects buf^1 for restage
    if (kt + 1 < nk) stage(buf ^ 1, kt + 1);
    f16x8 af[4], bf[4];
#pragma unroll
    for (int mi = 0; mi < 4; ++mi)
      af[mi] = *(const f16x8*)&As[buf][(wr * 64 + mi * 16 + ro) * 32 + ko];
#pragma unroll
    for (int ni = 0; ni < 4; ++ni)
      bf[ni] = *(const f16x8*)&Bs[buf][(wc * 64 + ni * 16 + ro) * 32 + ko];
#pragma unroll
    for (int mi = 0; mi < 4; ++mi)
#pragma unroll
      for (int ni = 0; ni < 4; ++ni)
        acc[mi][ni] = __builtin_amdgcn_mfma_f32_16x16x32_f16(
            af[mi], bf[ni], acc[mi][ni], 0, 0, 0);
  }

  // epilogue — C/D layout (verified m89/m91): col = lane&15, row = (lane>>4)*4+r
  const int rbase = m0 + wr * 64;
  const int cbase = n0 + wc * 64;
  const int rq = (lane >> 4) * 4;
  if (MODE == 1) {
    f16* CT = (f16*)C;
#pragma unroll
    for (int mi = 0; mi < 4; ++mi)
#pragma unroll
      for (int ni = 0; ni < 4; ++ni) {
        f16x4 pk;
#pragma unroll
        for (int r = 0; r < 4; ++r) pk[r] = (f16)(acc[mi][ni][r] * scale);
        const int colT = cbase + ni * 16 + ro;  // output col -> CT row
        const int rowT = rbase + mi * 16 + rq;  // output rows -> contiguous
        *(f16x4*)&CT[(size_t)colT * ldc + rowT] = pk;
      }
  } else {
#pragma unroll
    for (int mi = 0; mi < 4; ++mi)
#pragma unroll
      for (int ni = 0; ni < 4; ++ni)
#pragma unroll
        for (int r = 0; r < 4; ++r) {
          const int row = rbase + mi * 16 + rq + r;
          const int col = cbase + ni * 16 + ro;
          const float val = acc[mi][ni][r] * scale;
          if (MODE == 0)
            ((f16*)C)[(size_t)row * ldc + col] = (f16)val;
          else
            ((float*)C)[(size_t)row * ldc + col] = val;
        }
  }
}

// ---------------------------------------------------------------- softmax
__device__ inline float wave_max64(float v) {
#pragma unroll
  for (int o = 32; o > 0; o >>= 1) v = fmaxf(v, __shfl_xor(v, o, 64));
  return v;
}
__device__ inline float wave_sum64(float v) {
#pragma unroll
  for (int o = 32; o > 0; o >>= 1) v += __shfl_xor(v, o, 64);
  return v;
}

// One block (256 threads) per row of 8192 f16; in-place P = softmax(S).
__global__ __launch_bounds__(256) void softmax_rows(f16* __restrict__ S,
                                                    int ncols) {
  __shared__ float redm[4];
  __shared__ float reds[4];
  f16* p = S + (size_t)blockIdx.x * ncols;
  const int t = threadIdx.x, lane = t & 63, w = t >> 6;

  float v[32];
#pragma unroll
  for (int i = 0; i < 4; ++i) {
    f16x8 x = *(const f16x8*)&p[(i * 256 + t) * 8];
#pragma unroll
    for (int j = 0; j < 8; ++j) v[i * 8 + j] = (float)x[j];
  }
  float m = -1e30f;
#pragma unroll
  for (int i = 0; i < 32; ++i) m = fmaxf(m, v[i]);
  m = wave_max64(m);
  if (lane == 0) redm[w] = m;
  __syncthreads();
  m = fmaxf(fmaxf(redm[0], redm[1]), fmaxf(redm[2], redm[3]));

  float s = 0.f;
#pragma unroll
  for (int i = 0; i < 32; ++i) {
    v[i] = __expf(v[i] - m);
    s += v[i];
  }
  s = wave_sum64(s);
  if (lane == 0) reds[w] = s;
  __syncthreads();
  s = reds[0] + reds[1] + reds[2] + reds[3];
  const float inv = 1.0f / s;

#pragma unroll
  for (int i = 0; i < 4; ++i) {
    f16x8 x;
#pragma unroll
    for (int j = 0; j < 8; ++j) x[j] = (f16)(v[i * 8 + j] * inv);
    *(f16x8*)&p[(i * 256 + t) * 8] = x;
  }
}

// ---------------------------------------------------------------- launch
extern "C" void kernel_launch(void* const* d_in, const int* in_sizes, int n_in,
                              void* d_out, int out_size, void* d_ws,
                              size_t ws_size, hipStream_t stream) {
  (void)in_sizes;
  (void)n_in;
  (void)out_size;
  const float* X = (const float*)d_in[0];
  const float* WQ = (const float*)d_in[1];
  const float* WK = (const float*)d_in[2];
  const float* WV = (const float*)d_in[3];
  float* O = (float*)d_out;

  char* ws = (char*)d_ws;
  size_t off = 0;
  auto alloc = [&](size_t bytes) -> void* {
    void* p = ws + off;
    off += (bytes + 255) & ~(size_t)255;
    return p;
  };
  f16* Xh = (f16*)alloc((size_t)N_ROWS * D_DIM * 2);
  f16* WT = (f16*)alloc((size_t)3 * D_DIM * D_DIM * 2);
  f16* Q  = (f16*)alloc((size_t)N_ROWS * D_DIM * 2);
  f16* Kh = (f16*)alloc((size_t)N_ROWS * D_DIM * 2);
  f16* VT = (f16*)alloc((size_t)N_ROWS * D_DIM * 2);  // V transposed [D][N]

  size_t remain = (ws_size > off) ? (ws_size - off) : 0;
  int chunk = N_ROWS;  // q-rows of S materialized at once
  while (chunk > 128 && (size_t)chunk * N_ROWS * 2 + 256 > remain) chunk >>= 1;
  f16* S = (f16*)alloc((size_t)chunk * N_ROWS * 2);

  f32_to_f16_kernel<<<2048, 256, 0, stream>>>(X, Xh, N_ROWS * D_DIM / 4);
  transpose_w_kernel<<<dim3(16, 16, 3), 256, 0, stream>>>(WQ, WK, WV, WT);

  // Q = Xh*WQ, K = Xh*WK (f16), VT = (Xh*WV)^T (f16)
  gemm_tn<0><<<dim3(8, 64), 256, 0, stream>>>(Xh, D_DIM, WT, D_DIM, Q, D_DIM,
                                              D_DIM, 1.0f);
  gemm_tn<0><<<dim3(8, 64), 256, 0, stream>>>(Xh, D_DIM, WT + D_DIM * D_DIM,
                                              D_DIM, Kh, D_DIM, D_DIM, 1.0f);
  gemm_tn<1><<<dim3(8, 64), 256, 0, stream>>>(Xh, D_DIM, WT + 2 * D_DIM * D_DIM,
                                              D_DIM, VT, N_ROWS, D_DIM, 1.0f);

  const float sscale = 0.03125f;  // 1/sqrt(1024)
  for (int mc = 0; mc < N_ROWS; mc += chunk) {
    // S = (Q K^T) * scale   (K acts as BT: [kv][d] is k-contiguous)
    gemm_tn<0><<<dim3(64, chunk / 128), 256, 0, stream>>>(
        Q + (size_t)mc * D_DIM, D_DIM, Kh, D_DIM, S, N_ROWS, D_DIM, sscale);
    softmax_rows<<<chunk, 256, 0, stream>>>(S, N_ROWS);
    // O = P V   (VT[d][kv] is kv-contiguous -> BT operand)
    gemm_tn<2><<<dim3(8, chunk / 128), 256, 0, stream>>>(
        S, N_ROWS, VT, N_ROWS, O + (size_t)mc * D_DIM, D_DIM, N_ROWS, 1.0f);
  }
}

// Round 2
// 497.859 us; speedup vs baseline: 1.1112x; 1.1112x over previous
//
#include <hip/hip_runtime.h>

#define N_ROWS 8192
#define D_DIM  1024
#define SM_SHIFT 4.0f

typedef _Float16 f16;
typedef _Float16 f16x8 __attribute__((ext_vector_type(8)));
typedef _Float16 f16x4 __attribute__((ext_vector_type(4)));
typedef float    f32x4 __attribute__((ext_vector_type(4)));

__device__ __forceinline__ void gload_lds16(const void* g, void* l) {
  __builtin_amdgcn_global_load_lds(
      (const __attribute__((address_space(1))) void*)g,
      (__attribute__((address_space(3))) void*)l, 16, 0, 0);
}

// XCD-chunked block swizzle (m157): blocks with same (bid % 8) — which the HW
// round-robins onto one XCD — get consecutive tile ids => L2 panel reuse.
__device__ __forceinline__ int xcd_swz(int bid, int nb) {
  return (bid & 7) * (nb >> 3) + (bid >> 3);
}

// ---------------------------------------------------------------- converts
__global__ __launch_bounds__(256) void f32_to_f16_kernel(
    const float* __restrict__ in, f16* __restrict__ out, int n4) {
  for (int i = blockIdx.x * blockDim.x + threadIdx.x; i < n4;
       i += gridDim.x * blockDim.x) {
    float4 x = ((const float4*)in)[i];
    f16x4 h = {(f16)x.x, (f16)x.y, (f16)x.z, (f16)x.w};
    ((f16x4*)out)[i] = h;
  }
}

__global__ __launch_bounds__(256) void transpose_w_kernel(
    const float* __restrict__ w0, const float* __restrict__ w1,
    const float* __restrict__ w2, f16* __restrict__ WT) {
  const float* W = (blockIdx.z == 0) ? w0 : (blockIdx.z == 1) ? w1 : w2;
  f16* T = WT + (size_t)blockIdx.z * D_DIM * D_DIM;
  __shared__ float tile[64][65];
  const int r0 = blockIdx.y * 64, c0 = blockIdx.x * 64;
  const int t = threadIdx.x;
#pragma unroll
  for (int rep = 0; rep < 16; ++rep) {
    int idx = rep * 256 + t;
    int r = idx >> 6, c = idx & 63;
    tile[r][c] = W[(size_t)(r0 + r) * D_DIM + (c0 + c)];
  }
  __syncthreads();
#pragma unroll
  for (int rep = 0; rep < 16; ++rep) {
    int idx = rep * 256 + t;
    int r = idx >> 6, c = idx & 63;
    T[(size_t)(c0 + r) * D_DIM + (r0 + c)] = (f16)tile[c][r];
  }
}

// ---------------------------------------------------------------- GEMM core
// acc += A[128 x 32*nk] * BT[128 x 32*nk]^T, m97 structure (double-buffered
// LDS via global_load_lds width 16, 16x16x32 f16 MFMA, 4 waves 2x2).
__device__ __forceinline__ void gemm_mainloop(
    const f16* __restrict__ Abase, int lda, const f16* __restrict__ Bbase,
    int ldbt, int k0, int nk, f16* As, f16* Bs, f32x4 (&acc)[4][4], int tid) {
  const int lane = tid & 63;
  const int ro = lane & 15, ko = (lane >> 4) * 8;
  const int wr = tid >> 7, wc = (tid >> 6) & 1;

  auto stage = [&](int buf, int kt) {
    const int kk = k0 + kt * 32;
#pragma unroll
    for (int c = 0; c < 2; ++c) {
      const int q = c * 256 + tid;   // 512 x 16B chunks per 8KB tile
      const int row = q >> 2;
      const int col = (q & 3) * 8;
      gload_lds16(Abase + (size_t)row * lda + (kk + col),
                  As + buf * 4096 + q * 8);
      gload_lds16(Bbase + (size_t)row * ldbt + (kk + col),
                  Bs + buf * 4096 + q * 8);
    }
  };

  stage(0, 0);
  for (int kt = 0; kt < nk; ++kt) {
    const int buf = kt & 1;
    __syncthreads();  // drains vmcnt -> buf ready; protects buf^1 for restage
    if (kt + 1 < nk) stage(buf ^ 1, kt + 1);
    f16x8 af[4], bf[4];
#pragma unroll
    for (int mi = 0; mi < 4; ++mi)
      af[mi] =
          *(const f16x8*)(As + buf * 4096 + (wr * 64 + mi * 16 + ro) * 32 + ko);
#pragma unroll
    for (int ni = 0; ni < 4; ++ni)
      bf[ni] =
          *(const f16x8*)(Bs + buf * 4096 + (wc * 64 + ni * 16 + ro) * 32 + ko);
#pragma unroll
    for (int mi = 0; mi < 4; ++mi)
#pragma unroll
      for (int ni = 0; ni < 4; ++ni)
        acc[mi][ni] = __builtin_amdgcn_mfma_f32_16x16x32_f16(
            af[mi], bf[ni], acc[mi][ni], 0, 0, 0);
  }
}

// ---------------------------------------------------------------- QKV (batched)
__global__ __launch_bounds__(256) void gemm_qkv(
    const f16* __restrict__ Xh, const f16* __restrict__ WT,
    f16* __restrict__ Q, f16* __restrict__ Kh, f16* __restrict__ VT) {
  __shared__ f16 As[2 * 4096], Bs[2 * 4096];
  const int nid = xcd_swz(blockIdx.x, 8 * 64 * 3);
  const int nx = nid & 7, ny = (nid >> 3) & 63, z = nid >> 9;
  const int tid = threadIdx.x, lane = tid & 63;
  const int wr = tid >> 7, wc = (tid >> 6) & 1;

  f32x4 acc[4][4];
#pragma unroll
  for (int i = 0; i < 4; ++i)
#pragma unroll
    for (int j = 0; j < 4; ++j) acc[i][j] = (f32x4){0.f, 0.f, 0.f, 0.f};

  const f16* A = Xh + (size_t)ny * 128 * D_DIM;
  const f16* B = WT + (size_t)z * D_DIM * D_DIM + (size_t)nx * 128 * D_DIM;
  gemm_mainloop(A, D_DIM, B, D_DIM, 0, D_DIM / 32, As, Bs, acc, tid);

  const int ro = lane & 15, rq = (lane >> 4) * 4;
  const int rbase = ny * 128 + wr * 64, cbase = nx * 128 + wc * 64;
  if (z < 2) {
    f16* C = z ? Kh : Q;
#pragma unroll
    for (int mi = 0; mi < 4; ++mi)
#pragma unroll
      for (int ni = 0; ni < 4; ++ni)
#pragma unroll
        for (int r = 0; r < 4; ++r)
          C[(size_t)(rbase + mi * 16 + rq + r) * D_DIM + cbase + ni * 16 + ro] =
              (f16)acc[mi][ni][r];
  } else {
#pragma unroll
    for (int mi = 0; mi < 4; ++mi)
#pragma unroll
      for (int ni = 0; ni < 4; ++ni) {
        f16x4 pk;
#pragma unroll
        for (int r = 0; r < 4; ++r) pk[r] = (f16)acc[mi][ni][r];
        *(f16x4*)&VT[(size_t)(cbase + ni * 16 + ro) * N_ROWS + rbase + mi * 16 +
                     rq] = pk;
      }
  }
}

// ------------------------------------------------ S = exp(QK^T/32 - SHIFT)
// Also emits per-block row sums -> Lpart[row][64*2] (deterministic, no atomics)
__global__ __launch_bounds__(256) void gemm_s_exp(
    const f16* __restrict__ Q, const f16* __restrict__ Kh,
    f16* __restrict__ S, float* __restrict__ Lpart, int nyb) {
  __shared__ f16 As[2 * 4096], Bs[2 * 4096];
  const int nid = xcd_swz(blockIdx.x, 64 * nyb);
  const int nx = nid & 63, ny = nid >> 6;
  const int tid = threadIdx.x, lane = tid & 63;
  const int wr = tid >> 7, wc = (tid >> 6) & 1;

  f32x4 acc[4][4];
#pragma unroll
  for (int i = 0; i < 4; ++i)
#pragma unroll
    for (int j = 0; j < 4; ++j) acc[i][j] = (f32x4){0.f, 0.f, 0.f, 0.f};

  gemm_mainloop(Q + (size_t)ny * 128 * D_DIM, D_DIM,
                Kh + (size_t)nx * 128 * D_DIM, D_DIM, 0, D_DIM / 32, As, Bs,
                acc, tid);

  const int ro = lane & 15, rq = (lane >> 4) * 4;
  const float sc = 0.03125f;  // 1/sqrt(1024)
#pragma unroll
  for (int mi = 0; mi < 4; ++mi) {
    float rs[4] = {0.f, 0.f, 0.f, 0.f};
#pragma unroll
    for (int ni = 0; ni < 4; ++ni)
#pragma unroll
      for (int r = 0; r < 4; ++r) {
        float p = __expf(acc[mi][ni][r] * sc - SM_SHIFT);
        S[(size_t)(ny * 128 + wr * 64 + mi * 16 + rq + r) * N_ROWS + nx * 128 +
          wc * 64 + ni * 16 + ro] = (f16)p;
        rs[r] += p;
      }
#pragma unroll
    for (int r = 0; r < 4; ++r) {
      rs[r] += __shfl_xor(rs[r], 1, 64);
      rs[r] += __shfl_xor(rs[r], 2, 64);
      rs[r] += __shfl_xor(rs[r], 4, 64);
      rs[r] += __shfl_xor(rs[r], 8, 64);
    }
    if (ro == 0) {
#pragma unroll
      for (int r = 0; r < 4; ++r)
        Lpart[(size_t)(ny * 128 + wr * 64 + mi * 16 + rq + r) * 128 + nx * 2 +
              wc] = rs[r];
    }
  }
}

// ---------------------------------------------------------------- reduce l
__global__ __launch_bounds__(256) void reduce_l(const float* __restrict__ Lpart,
                                                float* __restrict__ linv,
                                                int rows) {
  const int w = (blockIdx.x * 256 + threadIdx.x) >> 6;  // one wave per row
  const int lane = threadIdx.x & 63;
  if (w >= rows) return;
  const float* p = Lpart + (size_t)w * 128;
  float s = p[lane] + p[lane + 64];
#pragma unroll
  for (int o = 32; o > 0; o >>= 1) s += __shfl_xor(s, o, 64);
  if (lane == 0) linv[w] = 1.0f / s;
}

// ---------------------------------------------------------------- PV (split-K)
__global__ __launch_bounds__(256) void gemm_pv(
    const f16* __restrict__ S, const f16* __restrict__ VT,
    float* __restrict__ Ppart, int nyb, int KS, int chunk) {
  __shared__ f16 As[2 * 4096], Bs[2 * 4096];
  const int nid = xcd_swz(blockIdx.x, (int)gridDim.x);
  const int nx = nid & 7, ny = (nid >> 3) % nyb, z = (nid >> 3) / nyb;
  const int tid = threadIdx.x, lane = tid & 63;
  const int wr = tid >> 7, wc = (tid >> 6) & 1;

  f32x4 acc[4][4];
#pragma unroll
  for (int i = 0; i < 4; ++i)
#pragma unroll
    for (int j = 0; j < 4; ++j) acc[i][j] = (f32x4){0.f, 0.f, 0.f, 0.f};

  gemm_mainloop(S + (size_t)ny * 128 * N_ROWS, N_ROWS,
                VT + (size_t)nx * 128 * N_ROWS, N_ROWS, z * KS, KS / 32, As,
                Bs, acc, tid);

  float* out = Ppart + (size_t)z * chunk * D_DIM;
  const int ro = lane & 15, rq = (lane >> 4) * 4;
#pragma unroll
  for (int mi = 0; mi < 4; ++mi)
#pragma unroll
    for (int ni = 0; ni < 4; ++ni)
#pragma unroll
      for (int r = 0; r < 4; ++r)
        out[(size_t)(ny * 128 + wr * 64 + mi * 16 + rq + r) * D_DIM + nx * 128 +
            wc * 64 + ni * 16 + ro] = acc[mi][ni][r];
}

// ---------------------------------------------------------------- reduce O
__global__ __launch_bounds__(256) void reduce_o(
    const float* __restrict__ Ppart, const float* __restrict__ linv,
    float* __restrict__ O, int rows, int sk) {
  const int n4 = rows * 256;  // float4 count (rows * 1024 / 4)
  const int stride = gridDim.x * blockDim.x;
  for (int i = blockIdx.x * 256 + threadIdx.x; i < n4; i += stride) {
    f32x4 s = ((const f32x4*)Ppart)[i];
    for (int t = 1; t < sk; ++t) s += ((const f32x4*)Ppart)[(size_t)t * n4 + i];
    const float il = linv[i >> 8];  // row = i*4/1024
    ((f32x4*)O)[i] = s * il;
  }
}

// ---------------------------------------------------------------- launch
extern "C" void kernel_launch(void* const* d_in, const int* in_sizes, int n_in,
                              void* d_out, int out_size, void* d_ws,
                              size_t ws_size, hipStream_t stream) {
  (void)in_sizes;
  (void)n_in;
  (void)out_size;
  const float* X = (const float*)d_in[0];
  const float* WQ = (const float*)d_in[1];
  const float* WK = (const float*)d_in[2];
  const float* WV = (const float*)d_in[3];
  float* O = (float*)d_out;

  // ---- workspace sizing: partials overlay the (dead-after-QKV) Xh/WT region
  const size_t fixedA = (size_t)N_ROWS * D_DIM * 2 + 3ull * D_DIM * D_DIM * 2;
  int chunk = 1024, sk = 1;
  const int pref[][2] = {{8192, 2}, {4096, 2}, {2048, 2}, {8192, 1},
                         {4096, 1}, {2048, 1}, {1024, 1}};
  for (int i = 0; i < 7; ++i) {
    const int c = pref[i][0], s = pref[i][1];
    size_t R = (size_t)s * c * D_DIM * 4;
    if (R < fixedA) R = fixedA;
    const size_t need = R + 3ull * N_ROWS * D_DIM * 2 + (size_t)c * N_ROWS * 2 +
                        (size_t)c * 128 * 4 + (size_t)c * 4 + 4096;
    if (need <= ws_size) {
      chunk = c;
      sk = s;
      break;
    }
  }

  char* base = (char*)d_ws;
  f16* Xh = (f16*)base;
  f16* WT = (f16*)(base + (size_t)N_ROWS * D_DIM * 2);
  float* Ppart = (float*)base;  // overlays Xh/WT (dead after QKV GEMMs)
  size_t R = (size_t)sk * chunk * D_DIM * 4;
  if (R < fixedA) R = fixedA;
  char* p = base + ((R + 255) & ~(size_t)255);
  f16* Q = (f16*)p;
  p += (size_t)N_ROWS * D_DIM * 2;
  f16* Kh = (f16*)p;
  p += (size_t)N_ROWS * D_DIM * 2;
  f16* VT = (f16*)p;
  p += (size_t)N_ROWS * D_DIM * 2;
  f16* S = (f16*)p;
  p += (size_t)chunk * N_ROWS * 2;
  float* Lpart = (float*)p;
  p += (size_t)chunk * 128 * 4;
  float* linv = (float*)p;

  f32_to_f16_kernel<<<2048, 256, 0, stream>>>(X, Xh, N_ROWS * D_DIM / 4);
  transpose_w_kernel<<<dim3(16, 16, 3), 256, 0, stream>>>(WQ, WK, WV, WT);
  gemm_qkv<<<8 * 64 * 3, 256, 0, stream>>>(Xh, WT, Q, Kh, VT);

  const int KS = N_ROWS / sk;
  for (int mc = 0; mc < N_ROWS; mc += chunk) {
    const int nyb = chunk / 128;
    gemm_s_exp<<<64 * nyb, 256, 0, stream>>>(Q + (size_t)mc * D_DIM, Kh, S,
                                             Lpart, nyb);
    reduce_l<<<(chunk + 3) / 4, 256, 0, stream>>>(Lpart, linv, chunk);
    gemm_pv<<<8 * nyb * sk, 256, 0, stream>>>(S, VT, Ppart, nyb, KS, chunk);
    reduce_o<<<1024, 256, 0, stream>>>(Ppart, linv, O + (size_t)mc * D_DIM,
                                       chunk, sk);
  }
}

// Round 3
// 484.331 us; speedup vs baseline: 1.1423x; 1.0279x over previous
//
#include <hip/hip_runtime.h>

#define N_ROWS 8192
#define D_DIM  1024
#define SM_SHIFT 4.0f

typedef _Float16 f16;
typedef _Float16 f16x8 __attribute__((ext_vector_type(8)));
typedef _Float16 f16x4 __attribute__((ext_vector_type(4)));
typedef float    f32x4 __attribute__((ext_vector_type(4)));

__device__ __forceinline__ void gload_lds16(const void* g, void* l) {
  __builtin_amdgcn_global_load_lds(
      (const __attribute__((address_space(1))) void*)g,
      (__attribute__((address_space(3))) void*)l, 16, 0, 0);
}

// XCD-chunked swizzle (m157): consecutive virtual ids land on one XCD.
__device__ __forceinline__ int xcd_swz(int bid, int nb) {
  return (bid & 7) * (nb >> 3) + (bid >> 3);
}

// XCD chunk + 8x8 supertile decode: consecutive co-XCD blocks form an 8x8
// tile group -> working set 8 A-panels + 8 B-panels (~4MB) fits one L2.
// Requires nx_t % 8 == 0 (or nx_t==8) and ny_t % 8 == 0.
__device__ __forceinline__ void tile2d(int bid, int nx_t, int ny_t, int& nx,
                                       int& ny) {
  const int v = xcd_swz(bid, nx_t * ny_t);
  const int g = v >> 6, w = v & 63;
  const int gpc = ny_t >> 3;  // 8-row groups per column of groups
  const int gx = g / gpc, gy = g - gx * gpc;
  nx = gx * 8 + (w & 7);
  ny = gy * 8 + (w >> 3);
}

// ---------------------------------------------------------------- converts
__global__ __launch_bounds__(256) void f32_to_f16_kernel(
    const float* __restrict__ in, f16* __restrict__ out, int n4) {
  for (int i = blockIdx.x * blockDim.x + threadIdx.x; i < n4;
       i += gridDim.x * blockDim.x) {
    float4 x = ((const float4*)in)[i];
    f16x4 h = {(f16)x.x, (f16)x.y, (f16)x.z, (f16)x.w};
    ((f16x4*)out)[i] = h;
  }
}

__global__ __launch_bounds__(256) void transpose_w_kernel(
    const float* __restrict__ w0, const float* __restrict__ w1,
    const float* __restrict__ w2, f16* __restrict__ WT) {
  const float* W = (blockIdx.z == 0) ? w0 : (blockIdx.z == 1) ? w1 : w2;
  f16* T = WT + (size_t)blockIdx.z * D_DIM * D_DIM;
  __shared__ float tile[64][65];
  const int r0 = blockIdx.y * 64, c0 = blockIdx.x * 64;
  const int t = threadIdx.x;
#pragma unroll
  for (int rep = 0; rep < 16; ++rep) {
    int idx = rep * 256 + t;
    int r = idx >> 6, c = idx & 63;
    tile[r][c] = W[(size_t)(r0 + r) * D_DIM + (c0 + c)];
  }
  __syncthreads();
#pragma unroll
  for (int rep = 0; rep < 16; ++rep) {
    int idx = rep * 256 + t;
    int r = idx >> 6, c = idx & 63;
    T[(size_t)(c0 + r) * D_DIM + (r0 + c)] = (f16)tile[c][r];
  }
}

// ---------------------------------------------------------------- GEMM core
// acc += A-tile * B-tile^T (both [128 x 32*nk], k-contiguous). m97 structure.
// SWAP=true computes the transposed C fragment (mfma operand order swapped):
// lane&15 indexes the M dim, (lane>>4)*4+r indexes the N dim -> each lane
// holds 4 CONSECUTIVE N-columns per acc reg quad => vectorized C stores.
template <bool SWAP>
__device__ __forceinline__ void gemm_mainloop(
    const f16* __restrict__ Abase, int lda, const f16* __restrict__ Bbase,
    int ldbt, int k0, int nk, f16* As, f16* Bs, f32x4 (&acc)[4][4], int tid) {
  const int lane = tid & 63;
  const int ro = lane & 15, ko = (lane >> 4) * 8;
  const int wr = tid >> 7, wc = (tid >> 6) & 1;

  auto stage = [&](int buf, int kt) {
    const int kk = k0 + kt * 32;
#pragma unroll
    for (int c = 0; c < 2; ++c) {
      const int q = c * 256 + tid;  // 512 x 16B chunks per 8KB tile
      const int row = q >> 2;
      const int col = (q & 3) * 8;
      gload_lds16(Abase + (size_t)row * lda + (kk + col),
                  As + buf * 4096 + q * 8);
      gload_lds16(Bbase + (size_t)row * ldbt + (kk + col),
                  Bs + buf * 4096 + q * 8);
    }
  };

  stage(0, 0);
  for (int kt = 0; kt < nk; ++kt) {
    const int buf = kt & 1;
    __syncthreads();  // drains vmcnt -> buf ready; protects buf^1 for restage
    if (kt + 1 < nk) stage(buf ^ 1, kt + 1);
    f16x8 af[4], bf[4];
#pragma unroll
    for (int mi = 0; mi < 4; ++mi)
      af[mi] =
          *(const f16x8*)(As + buf * 4096 + (wr * 64 + mi * 16 + ro) * 32 + ko);
#pragma unroll
    for (int ni = 0; ni < 4; ++ni)
      bf[ni] =
          *(const f16x8*)(Bs + buf * 4096 + (wc * 64 + ni * 16 + ro) * 32 + ko);
#pragma unroll
    for (int mi = 0; mi < 4; ++mi)
#pragma unroll
      for (int ni = 0; ni < 4; ++ni) {
        if (SWAP)
          acc[mi][ni] = __builtin_amdgcn_mfma_f32_16x16x32_f16(
              bf[ni], af[mi], acc[mi][ni], 0, 0, 0);
        else
          acc[mi][ni] = __builtin_amdgcn_mfma_f32_16x16x32_f16(
              af[mi], bf[ni], acc[mi][ni], 0, 0, 0);
      }
  }
}

#define ACC_INIT(acc)                                 \
  _Pragma("unroll") for (int i = 0; i < 4; ++i)       \
      _Pragma("unroll") for (int j = 0; j < 4; ++j)   \
          acc[i][j] = (f32x4){0.f, 0.f, 0.f, 0.f};

// ---------------------------------------------------------------- Q,K GEMM
__global__ __launch_bounds__(256) void gemm_qk(const f16* __restrict__ Xh,
                                               const f16* __restrict__ WT,
                                               f16* __restrict__ Q,
                                               f16* __restrict__ Kh) {
  __shared__ f16 As[2 * 4096], Bs[2 * 4096];
  const int v = xcd_swz(blockIdx.x, 1024);
  const int z = v >> 9;          // 0 -> Q, 1 -> K
  const int w9 = v & 511;
  const int g = w9 >> 6, w = w9 & 63;
  const int nx = w & 7, ny = g * 8 + (w >> 3);
  const int tid = threadIdx.x, lane = tid & 63;
  const int wr = tid >> 7, wc = (tid >> 6) & 1;

  f32x4 acc[4][4];
  ACC_INIT(acc);
  gemm_mainloop<true>(Xh + (size_t)ny * 128 * D_DIM, D_DIM,
                      WT + (size_t)z * D_DIM * D_DIM + (size_t)nx * 128 * D_DIM,
                      D_DIM, 0, D_DIM / 32, As, Bs, acc, tid);

  f16* C = z ? Kh : Q;
  const int ro = lane & 15, rq = (lane >> 4) * 4;
#pragma unroll
  for (int mi = 0; mi < 4; ++mi) {
    const size_t xr = ny * 128 + wr * 64 + mi * 16 + ro;
#pragma unroll
    for (int ni = 0; ni < 4; ++ni) {
      f16x4 pk;
#pragma unroll
      for (int r = 0; r < 4; ++r) pk[r] = (f16)acc[mi][ni][r];
      *(f16x4*)&C[xr * D_DIM + nx * 128 + wc * 64 + ni * 16 + rq] = pk;
    }
  }
}

// ---------------------------------------------------------------- V GEMM (T)
__global__ __launch_bounds__(256) void gemm_v(const f16* __restrict__ Xh,
                                              const f16* __restrict__ WT,
                                              f16* __restrict__ VT) {
  __shared__ f16 As[2 * 4096], Bs[2 * 4096];
  const int v = xcd_swz(blockIdx.x, 512);
  const int g = v >> 6, w = v & 63;
  const int nx = w & 7, ny = g * 8 + (w >> 3);
  const int tid = threadIdx.x, lane = tid & 63;
  const int wr = tid >> 7, wc = (tid >> 6) & 1;

  f32x4 acc[4][4];
  ACC_INIT(acc);
  gemm_mainloop<false>(Xh + (size_t)ny * 128 * D_DIM, D_DIM,
                       WT + 2ull * D_DIM * D_DIM + (size_t)nx * 128 * D_DIM,
                       D_DIM, 0, D_DIM / 32, As, Bs, acc, tid);

  // unswapped: lane holds 4 consecutive M-rows -> vectorized transposed store
  const int ro = lane & 15, rq = (lane >> 4) * 4;
#pragma unroll
  for (int mi = 0; mi < 4; ++mi)
#pragma unroll
    for (int ni = 0; ni < 4; ++ni) {
      f16x4 pk;
#pragma unroll
      for (int r = 0; r < 4; ++r) pk[r] = (f16)acc[mi][ni][r];
      const size_t d = nx * 128 + wc * 64 + ni * 16 + ro;
      *(f16x4*)&VT[d * N_ROWS + ny * 128 + wr * 64 + mi * 16 + rq] = pk;
    }
}

// ------------------------------------------------ S = exp(QK^T/32 - SHIFT)
// Per-block row sums -> Lpart[row][128] (deterministic, no atomics).
__global__ __launch_bounds__(256) void gemm_s_exp(
    const f16* __restrict__ Q, const f16* __restrict__ Kh, f16* __restrict__ S,
    float* __restrict__ Lpart, int nyb) {
  __shared__ f16 As[2 * 4096], Bs[2 * 4096];
  int nx, ny;
  tile2d(blockIdx.x, 64, nyb, nx, ny);
  const int tid = threadIdx.x, lane = tid & 63;
  const int wr = tid >> 7, wc = (tid >> 6) & 1;

  f32x4 acc[4][4];
  ACC_INIT(acc);
  gemm_mainloop<true>(Q + (size_t)ny * 128 * D_DIM, D_DIM,
                      Kh + (size_t)nx * 128 * D_DIM, D_DIM, 0, D_DIM / 32, As,
                      Bs, acc, tid);

  const int ro = lane & 15, rq = (lane >> 4) * 4;
  const float sc = 0.03125f;  // 1/sqrt(1024)
#pragma unroll
  for (int mi = 0; mi < 4; ++mi) {
    const size_t q = ny * 128 + wr * 64 + mi * 16 + ro;
    float rs = 0.f;
#pragma unroll
    for (int ni = 0; ni < 4; ++ni) {
      f16x4 pk;
#pragma unroll
      for (int r = 0; r < 4; ++r) {
        const float p = __expf(acc[mi][ni][r] * sc - SM_SHIFT);
        rs += p;
        pk[r] = (f16)p;
      }
      *(f16x4*)&S[q * N_ROWS + nx * 128 + wc * 64 + ni * 16 + rq] = pk;
    }
    rs += __shfl_xor(rs, 16, 64);
    rs += __shfl_xor(rs, 32, 64);
    if (lane < 16) Lpart[q * 128 + nx * 2 + wc] = rs;
  }
}

// ---------------------------------------------------------------- reduce l
__global__ __launch_bounds__(256) void reduce_l(const float* __restrict__ Lpart,
                                                float* __restrict__ linv,
                                                int rows) {
  const int w = (blockIdx.x * 256 + threadIdx.x) >> 6;  // one wave per row
  const int lane = threadIdx.x & 63;
  if (w >= rows) return;
  const float* p = Lpart + (size_t)w * 128;
  float s = p[lane] + p[lane + 64];
#pragma unroll
  for (int o = 32; o > 0; o >>= 1) s += __shfl_xor(s, o, 64);
  if (lane == 0) linv[w] = 1.0f / s;
}

// ---------------------------------------------------------------- PV (split-K)
__global__ __launch_bounds__(256) void gemm_pv(const f16* __restrict__ S,
                                               const f16* __restrict__ VT,
                                               float* __restrict__ Ppart,
                                               int nyb, int KS, int chunk) {
  __shared__ f16 As[2 * 4096], Bs[2 * 4096];
  const int nid = xcd_swz(blockIdx.x, (int)gridDim.x);
  const int nx = nid & 7, ny = (nid >> 3) % nyb, z = (nid >> 3) / nyb;
  const int tid = threadIdx.x, lane = tid & 63;
  const int wr = tid >> 7, wc = (tid >> 6) & 1;

  f32x4 acc[4][4];
  ACC_INIT(acc);
  gemm_mainloop<true>(S + (size_t)ny * 128 * N_ROWS, N_ROWS,
                      VT + (size_t)nx * 128 * N_ROWS, N_ROWS, z * KS, KS / 32,
                      As, Bs, acc, tid);

  float* out = Ppart + (size_t)z * chunk * D_DIM;
  const int ro = lane & 15, rq = (lane >> 4) * 4;
#pragma unroll
  for (int mi = 0; mi < 4; ++mi) {
    const size_t q = ny * 128 + wr * 64 + mi * 16 + ro;
#pragma unroll
    for (int ni = 0; ni < 4; ++ni)
      *(f32x4*)&out[q * D_DIM + nx * 128 + wc * 64 + ni * 16 + rq] =
          acc[mi][ni];
  }
}

// ---------------------------------------------------------------- reduce O
__global__ __launch_bounds__(256) void reduce_o(
    const float* __restrict__ Ppart, const float* __restrict__ linv,
    float* __restrict__ O, int rows, int sk) {
  const int n4 = rows * 256;  // float4 count (rows * 1024 / 4)
  const int stride = gridDim.x * blockDim.x;
  for (int i = blockIdx.x * 256 + threadIdx.x; i < n4; i += stride) {
    f32x4 s = ((const f32x4*)Ppart)[i];
    for (int t = 1; t < sk; ++t) s += ((const f32x4*)Ppart)[(size_t)t * n4 + i];
    const float il = linv[i >> 8];  // row = i*4/1024
    ((f32x4*)O)[i] = s * il;
  }
}

// ---------------------------------------------------------------- launch
extern "C" void kernel_launch(void* const* d_in, const int* in_sizes, int n_in,
                              void* d_out, int out_size, void* d_ws,
                              size_t ws_size, hipStream_t stream) {
  (void)in_sizes;
  (void)n_in;
  (void)out_size;
  const float* X = (const float*)d_in[0];
  const float* WQ = (const float*)d_in[1];
  const float* WK = (const float*)d_in[2];
  const float* WV = (const float*)d_in[3];
  float* O = (float*)d_out;

  // ---- workspace sizing: partials overlay the (dead-after-QKV) Xh/WT region
  const size_t fixedA = (size_t)N_ROWS * D_DIM * 2 + 3ull * D_DIM * D_DIM * 2;
  int chunk = 1024, sk = 1;
  const int pref[][2] = {{8192, 2}, {4096, 2}, {2048, 2}, {8192, 1},
                         {4096, 1}, {2048, 1}, {1024, 1}};
  for (int i = 0; i < 7; ++i) {
    const int c = pref[i][0], s = pref[i][1];
    size_t R = (size_t)s * c * D_DIM * 4;
    if (R < fixedA) R = fixedA;
    const size_t need = R + 3ull * N_ROWS * D_DIM * 2 + (size_t)c * N_ROWS * 2 +
                        (size_t)c * 128 * 4 + (size_t)c * 4 + 4096;
    if (need <= ws_size) {
      chunk = c;
      sk = s;
      break;
    }
  }

  char* base = (char*)d_ws;
  f16* Xh = (f16*)base;
  f16* WT = (f16*)(base + (size_t)N_ROWS * D_DIM * 2);
  float* Ppart = (float*)base;  // overlays Xh/WT (dead after QKV GEMMs)
  size_t R = (size_t)sk * chunk * D_DIM * 4;
  if (R < fixedA) R = fixedA;
  char* p = base + ((R + 255) & ~(size_t)255);
  f16* Q = (f16*)p;
  p += (size_t)N_ROWS * D_DIM * 2;
  f16* Kh = (f16*)p;
  p += (size_t)N_ROWS * D_DIM * 2;
  f16* VT = (f16*)p;
  p += (size_t)N_ROWS * D_DIM * 2;
  f16* S = (f16*)p;
  p += (size_t)chunk * N_ROWS * 2;
  float* Lpart = (float*)p;
  p += (size_t)chunk * 128 * 4;
  float* linv = (float*)p;

  f32_to_f16_kernel<<<2048, 256, 0, stream>>>(X, Xh, N_ROWS * D_DIM / 4);
  transpose_w_kernel<<<dim3(16, 16, 3), 256, 0, stream>>>(WQ, WK, WV, WT);
  gemm_qk<<<1024, 256, 0, stream>>>(Xh, WT, Q, Kh);
  gemm_v<<<512, 256, 0, stream>>>(Xh, WT, VT);

  const int KS = N_ROWS / sk;
  for (int mc = 0; mc < N_ROWS; mc += chunk) {
    const int nyb = chunk / 128;
    gemm_s_exp<<<64 * nyb, 256, 0, stream>>>(Q + (size_t)mc * D_DIM, Kh, S,
                                             Lpart, nyb);
    reduce_l<<<(chunk + 3) / 4, 256, 0, stream>>>(Lpart, linv, chunk);
    gemm_pv<<<8 * nyb * sk, 256, 0, stream>>>(S, VT, Ppart, nyb, KS, chunk);
    reduce_o<<<1024, 256, 0, stream>>>(Ppart, linv, O + (size_t)mc * D_DIM,
                                       chunk, sk);
  }
}

// Round 5
// 464.859 us; speedup vs baseline: 1.1901x; 1.0419x over previous
//
#include <hip/hip_runtime.h>

#define N_ROWS 8192
#define D_DIM  1024
#define SM_SHIFT 4.0f

typedef _Float16 f16;
typedef _Float16 f16x8 __attribute__((ext_vector_type(8)));
typedef _Float16 f16x4 __attribute__((ext_vector_type(4)));
typedef float    f32x4 __attribute__((ext_vector_type(4)));

// offset=0 form only — the exact intrinsic usage verified in rounds 1-3.
__device__ __forceinline__ void gload16(const void* g, void* l) {
  __builtin_amdgcn_global_load_lds(
      (const __attribute__((address_space(1))) void*)g,
      (__attribute__((address_space(3))) void*)l, 16, 0, 0);
}

// XCD-chunked swizzle (m157): consecutive virtual ids land on one XCD.
__device__ __forceinline__ int xcd_swz(int bid, int nb) {
  return (bid & 7) * (nb >> 3) + (bid >> 3);
}

// 4x4 supertile of 256^2 tiles per co-XCD chunk: 4 A-panels + 4 B-panels
// (256x1024x2B = 512KB each) = 4MB = one XCD L2. Requires ny_t % 4 == 0.
__device__ __forceinline__ void tile2d4(int bid, int ny_t, int& nx, int& ny) {
  const int v = xcd_swz(bid, 32 * ny_t);
  const int g = v >> 4, w = v & 15;
  const int gpc = ny_t >> 2;
  const int gx = g / gpc, gy = g - gx * gpc;
  nx = gx * 4 + (w & 3);
  ny = gy * 4 + (w >> 2);
}

// ---------------------------------------------------------------- converts
__global__ __launch_bounds__(256) void f32_to_f16_kernel(
    const float* __restrict__ in, f16* __restrict__ out, int n4) {
  for (int i = blockIdx.x * blockDim.x + threadIdx.x; i < n4;
       i += gridDim.x * blockDim.x) {
    float4 x = ((const float4*)in)[i];
    f16x4 h = {(f16)x.x, (f16)x.y, (f16)x.z, (f16)x.w};
    ((f16x4*)out)[i] = h;
  }
}

__global__ __launch_bounds__(256) void transpose_w_kernel(
    const float* __restrict__ w0, const float* __restrict__ w1,
    const float* __restrict__ w2, f16* __restrict__ WT) {
  const float* W = (blockIdx.z == 0) ? w0 : (blockIdx.z == 1) ? w1 : w2;
  f16* T = WT + (size_t)blockIdx.z * D_DIM * D_DIM;
  __shared__ float tile[64][65];
  const int r0 = blockIdx.y * 64, c0 = blockIdx.x * 64;
  const int t = threadIdx.x;
#pragma unroll
  for (int rep = 0; rep < 16; ++rep) {
    int idx = rep * 256 + t;
    int r = idx >> 6, c = idx & 63;
    tile[r][c] = W[(size_t)(r0 + r) * D_DIM + (c0 + c)];
  }
  __syncthreads();
#pragma unroll
  for (int rep = 0; rep < 16; ++rep) {
    int idx = rep * 256 + t;
    int r = idx >> 6, c = idx & 63;
    T[(size_t)(c0 + r) * D_DIM + (r0 + c)] = (f16)tile[c][r];
  }
}

// --------------------------------------------------- 256^2 ring-3 main loop
// C[256x256] += A[256xK] * BT[256xK]^T, BK=32. 8 waves (2M x 4N), wave tile
// 128x64. LDS: 3-buffer ring (96 KiB) staged via global_load_lds (offset=0,
// pointers advanced in code — rounds-1-3-verified usage). One builtin
// s_barrier per K-step with COUNTED s_waitcnt vmcnt(4): tile kt+1/kt+2 loads
// stay in flight across the barrier (T3/T4). setprio around MFMA (T5).
// Hazard proof: reads of buf b complete (lgkmcnt(0)) before the next barrier;
// stage into b happens only 2 barriers after its last reader's barrier.
template <bool SWAP>
__device__ __forceinline__ void mainloop256(const f16* __restrict__ Ag, int lda,
                                            const f16* __restrict__ Bg,
                                            int ldbt, int nk, f16* LA, f16* LB,
                                            f32x4 (&acc)[8][4], int tid) {
  const int lane = tid & 63;
  const int wr = tid >> 8, wc = (tid >> 6) & 3;
  const int ro = lane & 15;
  const int ko = (lane >> 4) << 4;  // byte offset of k-slot within 64B row
  const int r0 = tid >> 2;          // staged tile row (0..127)
  const int c0 = (tid & 3) * 8;     // staged col offset, f16 elems
  const f16* a0 = Ag + (size_t)r0 * lda + c0;
  const f16* a1 = Ag + (size_t)(r0 + 128) * lda + c0;
  const f16* b0 = Bg + (size_t)r0 * ldbt + c0;
  const f16* b1 = Bg + (size_t)(r0 + 128) * ldbt + c0;
  char* la = (char*)LA;
  char* lb = (char*)LB;
  const int t16 = tid * 16;

  // stage next K-tile into ring buffer buf; advances global pointers.
  auto stage = [&](int buf) {
    char* A = la + buf * 16384;
    char* B = lb + buf * 16384;
    gload16(a0, A + t16);
    gload16(b0, B + t16);
    gload16(a1, A + 8192 + t16);
    gload16(b1, B + 8192 + t16);
    a0 += 32;
    a1 += 32;
    b0 += 32;
    b1 += 32;
  };

  stage(0);
  if (nk > 1) stage(1);

  int bR = 0;
  for (int kt = 0; kt < nk; ++kt) {
    // tile kt's 4 oldest loads done; tile kt+1's 4 may stay in flight (T4)
    if (kt + 1 < nk)
      asm volatile("s_waitcnt vmcnt(4)" ::: "memory");
    else
      asm volatile("s_waitcnt vmcnt(0)" ::: "memory");
    __builtin_amdgcn_s_barrier();
    __builtin_amdgcn_sched_barrier(0);
    if (kt + 2 < nk) {  // stage tile kt+2 into tile kt-1's buffer (free now)
      int bS = bR + 2;
      if (bS >= 3) bS -= 3;
      stage(bS);
    }
    const char* ab = la + bR * 16384;
    const char* bb = lb + bR * 16384;
    f16x8 af[8], bf[4];
#pragma unroll
    for (int mi = 0; mi < 8; ++mi)
      af[mi] = *(const f16x8*)(ab + (wr * 128 + mi * 16 + ro) * 64 + ko);
#pragma unroll
    for (int ni = 0; ni < 4; ++ni)
      bf[ni] = *(const f16x8*)(bb + (wc * 64 + ni * 16 + ro) * 64 + ko);
    asm volatile("s_waitcnt lgkmcnt(0)" ::: "memory");
    __builtin_amdgcn_sched_barrier(0);  // rule #18: keep MFMA below the wait
    __builtin_amdgcn_s_setprio(1);
#pragma unroll
    for (int mi = 0; mi < 8; ++mi)
#pragma unroll
      for (int ni = 0; ni < 4; ++ni)
        acc[mi][ni] =
            SWAP ? __builtin_amdgcn_mfma_f32_16x16x32_f16(bf[ni], af[mi],
                                                          acc[mi][ni], 0, 0, 0)
                 : __builtin_amdgcn_mfma_f32_16x16x32_f16(af[mi], bf[ni],
                                                          acc[mi][ni], 0, 0, 0);
    __builtin_amdgcn_s_setprio(0);
    bR = (bR == 2) ? 0 : bR + 1;
  }
}

#define ACC_INIT8(acc)                                \
  _Pragma("unroll") for (int i = 0; i < 8; ++i)       \
      _Pragma("unroll") for (int j = 0; j < 4; ++j)   \
          acc[i][j] = (f32x4){0.f, 0.f, 0.f, 0.f};

// ---------------------------------------------------------------- QKV GEMM
__global__ __launch_bounds__(512, 2) void gemm_qkv(
    const f16* __restrict__ Xh, const f16* __restrict__ WT,
    f16* __restrict__ Q, f16* __restrict__ Kh, f16* __restrict__ VT) {
  __shared__ f16 LA[3][8192], LB[3][8192];
  const int v = xcd_swz(blockIdx.x, 384);
  const int z = v >> 7, r = v & 127;
  const int nx = r & 3, ny = r >> 2;
  const int tid = threadIdx.x, lane = tid & 63;
  const int wr = tid >> 8, wc = (tid >> 6) & 3;
  const int ro = lane & 15, rq = (lane >> 4) * 4;

  const f16* A = Xh + (size_t)ny * 256 * D_DIM;
  const f16* B = WT + (size_t)z * D_DIM * D_DIM + (size_t)nx * 256 * D_DIM;

  f32x4 acc[8][4];
  ACC_INIT8(acc);
  if (z < 2) {
    mainloop256<true>(A, D_DIM, B, D_DIM, D_DIM / 32, &LA[0][0], &LB[0][0],
                      acc, tid);
    f16* C = z ? Kh : Q;
#pragma unroll
    for (int mi = 0; mi < 8; ++mi) {
      const size_t xr = ny * 256 + wr * 128 + mi * 16 + ro;
#pragma unroll
      for (int ni = 0; ni < 4; ++ni) {
        f16x4 pk;
#pragma unroll
        for (int rr = 0; rr < 4; ++rr) pk[rr] = (f16)acc[mi][ni][rr];
        *(f16x4*)&C[xr * D_DIM + nx * 256 + wc * 64 + ni * 16 + rq] = pk;
      }
    }
  } else {
    mainloop256<false>(A, D_DIM, B, D_DIM, D_DIM / 32, &LA[0][0], &LB[0][0],
                       acc, tid);
    // unswapped: lane holds 4 consecutive M-rows -> vectorized VT store
#pragma unroll
    for (int mi = 0; mi < 8; ++mi)
#pragma unroll
      for (int ni = 0; ni < 4; ++ni) {
        f16x4 pk;
#pragma unroll
        for (int rr = 0; rr < 4; ++rr) pk[rr] = (f16)acc[mi][ni][rr];
        const size_t d = nx * 256 + wc * 64 + ni * 16 + ro;
        *(f16x4*)&VT[d * N_ROWS + ny * 256 + wr * 128 + mi * 16 + rq] = pk;
      }
  }
}

// ------------------------------------------------ S = exp(QK^T/32 - SHIFT)
// Per-block row sums -> Lpart[row][128] (deterministic, no atomics).
__global__ __launch_bounds__(512, 2) void gemm_s_exp(
    const f16* __restrict__ Q, const f16* __restrict__ Kh, f16* __restrict__ S,
    float* __restrict__ Lpart, int nyb) {
  __shared__ f16 LA[3][8192], LB[3][8192];
  int nx, ny;
  tile2d4(blockIdx.x, nyb, nx, ny);
  const int tid = threadIdx.x, lane = tid & 63;
  const int wr = tid >> 8, wc = (tid >> 6) & 3;
  const int ro = lane & 15, rq = (lane >> 4) * 4;

  f32x4 acc[8][4];
  ACC_INIT8(acc);
  mainloop256<true>(Q + (size_t)ny * 256 * D_DIM, D_DIM,
                    Kh + (size_t)nx * 256 * D_DIM, D_DIM, D_DIM / 32,
                    &LA[0][0], &LB[0][0], acc, tid);

  const float sc = 0.03125f;  // 1/sqrt(1024)
#pragma unroll
  for (int mi = 0; mi < 8; ++mi) {
    const size_t q = ny * 256 + wr * 128 + mi * 16 + ro;
    f16* srow = S + q * N_ROWS + nx * 256 + wc * 64 + rq;
    float rs = 0.f;
#pragma unroll
    for (int ni = 0; ni < 4; ++ni) {
      f16x4 pk;
#pragma unroll
      for (int rr = 0; rr < 4; ++rr) {
        const float p = __expf(acc[mi][ni][rr] * sc - SM_SHIFT);
        rs += p;
        pk[rr] = (f16)p;
      }
      *(f16x4*)&srow[ni * 16] = pk;
    }
    rs += __shfl_xor(rs, 16, 64);
    rs += __shfl_xor(rs, 32, 64);
    if (lane < 16) Lpart[q * 128 + nx * 4 + wc] = rs;
  }
}

// ---------------------------------------------------------------- reduce l
__global__ __launch_bounds__(256) void reduce_l(const float* __restrict__ Lpart,
                                                float* __restrict__ linv,
                                                int rows) {
  const int w = (blockIdx.x * 256 + threadIdx.x) >> 6;  // one wave per row
  const int lane = threadIdx.x & 63;
  if (w >= rows) return;
  const float* p = Lpart + (size_t)w * 128;
  float s = p[lane] + p[lane + 64];
#pragma unroll
  for (int o = 32; o > 0; o >>= 1) s += __shfl_xor(s, o, 64);
  if (lane == 0) linv[w] = 1.0f / s;
}

// ---------------------------------------------------------------- PV
__global__ __launch_bounds__(512, 2) void gemm_pv(const f16* __restrict__ S,
                                                  const f16* __restrict__ VT,
                                                  float* __restrict__ Ppart,
                                                  int nyb, int KS, int chunk) {
  __shared__ f16 LA[3][8192], LB[3][8192];
  const int nid = xcd_swz(blockIdx.x, (int)gridDim.x);
  const int nx = nid & 3, ny = (nid >> 2) % nyb, z = (nid >> 2) / nyb;
  const int tid = threadIdx.x, lane = tid & 63;
  const int wr = tid >> 8, wc = (tid >> 6) & 3;
  const int ro = lane & 15, rq = (lane >> 4) * 4;

  f32x4 acc[8][4];
  ACC_INIT8(acc);
  mainloop256<true>(S + (size_t)ny * 256 * N_ROWS + (size_t)z * KS, N_ROWS,
                    VT + (size_t)nx * 256 * N_ROWS + (size_t)z * KS, N_ROWS,
                    KS / 32, &LA[0][0], &LB[0][0], acc, tid);

  float* out = Ppart + (size_t)z * chunk * D_DIM;
#pragma unroll
  for (int mi = 0; mi < 8; ++mi) {
    const size_t q = ny * 256 + wr * 128 + mi * 16 + ro;
#pragma unroll
    for (int ni = 0; ni < 4; ++ni)
      *(f32x4*)&out[q * D_DIM + nx * 256 + wc * 64 + ni * 16 + rq] =
          acc[mi][ni];
  }
}

// ---------------------------------------------------------------- reduce O
__global__ __launch_bounds__(256) void reduce_o(
    const float* __restrict__ Ppart, const float* __restrict__ linv,
    float* __restrict__ O, int rows, int sk) {
  const int n4 = rows * 256;  // float4 count (rows * 1024 / 4)
  const int stride = gridDim.x * blockDim.x;
  for (int i = blockIdx.x * 256 + threadIdx.x; i < n4; i += stride) {
    f32x4 s = ((const f32x4*)Ppart)[i];
    for (int t = 1; t < sk; ++t) s += ((const f32x4*)Ppart)[(size_t)t * n4 + i];
    const float il = linv[i >> 8];  // row = i*4/1024
    ((f32x4*)O)[i] = s * il;
  }
}

// ---------------------------------------------------------------- launch
extern "C" void kernel_launch(void* const* d_in, const int* in_sizes, int n_in,
                              void* d_out, int out_size, void* d_ws,
                              size_t ws_size, hipStream_t stream) {
  (void)in_sizes;
  (void)n_in;
  (void)out_size;
  const float* X = (const float*)d_in[0];
  const float* WQ = (const float*)d_in[1];
  const float* WK = (const float*)d_in[2];
  const float* WV = (const float*)d_in[3];
  float* O = (float*)d_out;

  // ---- workspace sizing: partials overlay the (dead-after-QKV) Xh/WT region
  const size_t fixedA = (size_t)N_ROWS * D_DIM * 2 + 3ull * D_DIM * D_DIM * 2;
  int chunk = 1024, sk = 1;
  const int pref[][2] = {{8192, 2}, {4096, 2}, {2048, 2}, {8192, 1},
                         {4096, 1}, {2048, 1}, {1024, 1}};
  for (int i = 0; i < 7; ++i) {
    const int c = pref[i][0], s = pref[i][1];
    size_t R = (size_t)s * c * D_DIM * 4;
    if (R < fixedA) R = fixedA;
    const size_t need = R + 3ull * N_ROWS * D_DIM * 2 + (size_t)c * N_ROWS * 2 +
                        (size_t)c * 128 * 4 + (size_t)c * 4 + 4096;
    if (need <= ws_size) {
      chunk = c;
      sk = s;
      break;
    }
  }

  char* base = (char*)d_ws;
  f16* Xh = (f16*)base;
  f16* WT = (f16*)(base + (size_t)N_ROWS * D_DIM * 2);
  float* Ppart = (float*)base;  // overlays Xh/WT (dead after QKV GEMMs)
  size_t R = (size_t)sk * chunk * D_DIM * 4;
  if (R < fixedA) R = fixedA;
  char* p = base + ((R + 255) & ~(size_t)255);
  f16* Q = (f16*)p;
  p += (size_t)N_ROWS * D_DIM * 2;
  f16* Kh = (f16*)p;
  p += (size_t)N_ROWS * D_DIM * 2;
  f16* VT = (f16*)p;
  p += (size_t)N_ROWS * D_DIM * 2;
  f16* S = (f16*)p;
  p += (size_t)chunk * N_ROWS * 2;
  float* Lpart = (float*)p;
  p += (size_t)chunk * 128 * 4;
  float* linv = (float*)p;

  f32_to_f16_kernel<<<2048, 256, 0, stream>>>(X, Xh, N_ROWS * D_DIM / 4);
  transpose_w_kernel<<<dim3(16, 16, 3), 256, 0, stream>>>(WQ, WK, WV, WT);
  gemm_qkv<<<384, 512, 0, stream>>>(Xh, WT, Q, Kh, VT);

  const int KS = N_ROWS / sk;
  for (int mc = 0; mc < N_ROWS; mc += chunk) {
    const int nyb = chunk / 256;
    gemm_s_exp<<<32 * nyb, 512, 0, stream>>>(Q + (size_t)mc * D_DIM, Kh, S,
                                             Lpart, nyb);
    reduce_l<<<(chunk + 3) / 4, 256, 0, stream>>>(Lpart, linv, chunk);
    gemm_pv<<<4 * nyb * sk, 512, 0, stream>>>(S, VT, Ppart, nyb, KS, chunk);
    reduce_o<<<1024, 256, 0, stream>>>(Ppart, linv, O + (size_t)mc * D_DIM,
                                       chunk, sk);
  }
}

// Round 6
// 403.012 us; speedup vs baseline: 1.3728x; 1.1535x over previous
//
#include <hip/hip_runtime.h>

#define N_ROWS 8192
#define D_DIM  1024
#define SM_SHIFT 4.0f

typedef _Float16 f16;
typedef _Float16 f16x8 __attribute__((ext_vector_type(8)));
typedef _Float16 f16x4 __attribute__((ext_vector_type(4)));
typedef float    f32x4 __attribute__((ext_vector_type(4)));

// offset=0 form only — the exact intrinsic usage verified in rounds 1-3,5.
__device__ __forceinline__ void gload16(const void* g, void* l) {
  __builtin_amdgcn_global_load_lds(
      (const __attribute__((address_space(1))) void*)g,
      (__attribute__((address_space(3))) void*)l, 16, 0, 0);
}

// XCD-chunked swizzle (m157): consecutive virtual ids land on one XCD.
__device__ __forceinline__ int xcd_swz(int bid, int nb) {
  return (bid & 7) * (nb >> 3) + (bid >> 3);
}

// 4x4 supertile of 256^2 tiles per co-XCD chunk: 4 A-panels + 4 B-panels
// (256x1024x2B = 512KB each) = 4MB = one XCD L2. Requires ny_t % 4 == 0.
__device__ __forceinline__ void tile2d4(int bid, int ny_t, int& nx, int& ny) {
  const int v = xcd_swz(bid, 32 * ny_t);
  const int g = v >> 4, w = v & 15;
  const int gpc = ny_t >> 2;
  const int gx = g / gpc, gy = g - gx * gpc;
  nx = gx * 4 + (w & 3);
  ny = gy * 4 + (w >> 2);
}

// ---------------------------------------------------------------- converts
__global__ __launch_bounds__(256) void f32_to_f16_kernel(
    const float* __restrict__ in, f16* __restrict__ out, int n4) {
  for (int i = blockIdx.x * blockDim.x + threadIdx.x; i < n4;
       i += gridDim.x * blockDim.x) {
    float4 x = ((const float4*)in)[i];
    f16x4 h = {(f16)x.x, (f16)x.y, (f16)x.z, (f16)x.w};
    ((f16x4*)out)[i] = h;
  }
}

__global__ __launch_bounds__(256) void transpose_w_kernel(
    const float* __restrict__ w0, const float* __restrict__ w1,
    const float* __restrict__ w2, f16* __restrict__ WT) {
  const float* W = (blockIdx.z == 0) ? w0 : (blockIdx.z == 1) ? w1 : w2;
  f16* T = WT + (size_t)blockIdx.z * D_DIM * D_DIM;
  __shared__ float tile[64][65];
  const int r0 = blockIdx.y * 64, c0 = blockIdx.x * 64;
  const int t = threadIdx.x;
#pragma unroll
  for (int rep = 0; rep < 16; ++rep) {
    int idx = rep * 256 + t;
    int r = idx >> 6, c = idx & 63;
    tile[r][c] = W[(size_t)(r0 + r) * D_DIM + (c0 + c)];
  }
  __syncthreads();
#pragma unroll
  for (int rep = 0; rep < 16; ++rep) {
    int idx = rep * 256 + t;
    int r = idx >> 6, c = idx & 63;
    T[(size_t)(c0 + r) * D_DIM + (r0 + c)] = (f16)tile[c][r];
  }
}

// --------------------------------------------- 256^2 BK=64 swizzled mainloop
// C[256x256] += A[256xK] * BT[256xK]^T, K-step 64. 8 waves (2M x 4N), wave
// tile 128x64. LDS: 2 buffers x (A 32KB + B 32KB) = 128KB, rows of 128B.
// T2 bank-conflict fix (rule 21, both-sides): LDS slot (row, jj) holds global
// 16B-column jj ^ (row&7); staging keeps the linear global_load_lds dest and
// pre-swizzles the global SOURCE column (row&7 invariant per thread across
// the 4 sweeps); ds_read XORs the same mask -> 8 consecutive lanes (8
// consecutive rows, same k-slot) spread over all 8 bank groups.
// Sync (T3/T4): counted vmcnt(8) keeps next tile's 8 loads in flight across
// barrier#1; barrier#2 after the MFMAs makes restaging the buffer safe
// (every wave's ds_reads completed via lgkmcnt(0) before it).
template <bool SWAP>
__device__ __forceinline__ void mainloop256(const f16* __restrict__ Ag, int lda,
                                            const f16* __restrict__ Bg,
                                            int ldbt, int nk, f16* LA, f16* LB,
                                            f32x4 (&acc)[8][4], int tid) {
  const int lane = tid & 63;
  const int wr = tid >> 8, wc = (tid >> 6) & 3;
  const int ro = lane & 15;
  const int jj0 = (((lane >> 4) ^ (ro & 7)) << 4);  // swizzled 16B col, h=0
  const int rs = tid >> 3;                          // staging row (0..63)
  const int ce = ((tid & 7) ^ (rs & 7)) * 8;        // pre-swizzled src col
  const f16* a[4];
  const f16* b[4];
#pragma unroll
  for (int s = 0; s < 4; ++s) {
    a[s] = Ag + (size_t)(rs + 64 * s) * lda + ce;
    b[s] = Bg + (size_t)(rs + 64 * s) * ldbt + ce;
  }
  char* la = (char*)LA;
  char* lb = (char*)LB;
  const int t16 = tid * 16;

  // stage next K64-tile (A 32KB + B 32KB, 8 loads) into buffer buf
  auto stage = [&](int buf) {
    char* A = la + buf * 32768;
    char* B = lb + buf * 32768;
#pragma unroll
    for (int s = 0; s < 4; ++s) {
      gload16(a[s], A + s * 8192 + t16);
      gload16(b[s], B + s * 8192 + t16);
    }
#pragma unroll
    for (int s = 0; s < 4; ++s) {
      a[s] += 64;
      b[s] += 64;
    }
  };

  stage(0);

  for (int kt = 0; kt < nk; ++kt) {
    const int buf = kt & 1;
    if (kt + 1 < nk) {
      stage(buf ^ 1);  // 8 newest loads stay in flight across the barrier
      asm volatile("s_waitcnt vmcnt(8)" ::: "memory");  // tile kt landed
    } else {
      asm volatile("s_waitcnt vmcnt(0)" ::: "memory");
    }
    __builtin_amdgcn_s_barrier();  // #1: tile kt visible to all waves
    __builtin_amdgcn_sched_barrier(0);
    const char* ab = la + buf * 32768;
    const char* bb = lb + buf * 32768;
#pragma unroll
    for (int h = 0; h < 2; ++h) {
      const int jo = jj0 ^ (h << 6);  // h=1: k-slot +4 -> XOR 64 bytes
      f16x8 af[8], bf[4];
#pragma unroll
      for (int mi = 0; mi < 8; ++mi)
        af[mi] = *(const f16x8*)(ab + (wr * 128 + mi * 16 + ro) * 128 + jo);
#pragma unroll
      for (int ni = 0; ni < 4; ++ni)
        bf[ni] = *(const f16x8*)(bb + (wc * 64 + ni * 16 + ro) * 128 + jo);
      asm volatile("s_waitcnt lgkmcnt(0)" ::: "memory");
      __builtin_amdgcn_sched_barrier(0);  // rule #18: pin MFMA below the wait
      __builtin_amdgcn_s_setprio(1);
#pragma unroll
      for (int mi = 0; mi < 8; ++mi)
#pragma unroll
        for (int ni = 0; ni < 4; ++ni)
          acc[mi][ni] =
              SWAP ? __builtin_amdgcn_mfma_f32_16x16x32_f16(
                         bf[ni], af[mi], acc[mi][ni], 0, 0, 0)
                   : __builtin_amdgcn_mfma_f32_16x16x32_f16(
                         af[mi], bf[ni], acc[mi][ni], 0, 0, 0);
      __builtin_amdgcn_s_setprio(0);
    }
    __builtin_amdgcn_s_barrier();  // #2: all reads of buf done -> restage safe
  }
}

#define ACC_INIT8(acc)                                \
  _Pragma("unroll") for (int i = 0; i < 8; ++i)       \
      _Pragma("unroll") for (int j = 0; j < 4; ++j)   \
          acc[i][j] = (f32x4){0.f, 0.f, 0.f, 0.f};

// ---------------------------------------------------------------- QKV GEMM
__global__ __launch_bounds__(512, 2) void gemm_qkv(
    const f16* __restrict__ Xh, const f16* __restrict__ WT,
    f16* __restrict__ Q, f16* __restrict__ Kh, f16* __restrict__ VT) {
  __shared__ f16 LA[2][16384], LB[2][16384];
  const int v = xcd_swz(blockIdx.x, 384);
  const int z = v >> 7, r = v & 127;
  const int nx = r & 3, ny = r >> 2;
  const int tid = threadIdx.x, lane = tid & 63;
  const int wr = tid >> 8, wc = (tid >> 6) & 3;
  const int ro = lane & 15, rq = (lane >> 4) * 4;

  const f16* A = Xh + (size_t)ny * 256 * D_DIM;
  const f16* B = WT + (size_t)z * D_DIM * D_DIM + (size_t)nx * 256 * D_DIM;

  f32x4 acc[8][4];
  ACC_INIT8(acc);
  if (z < 2) {
    mainloop256<true>(A, D_DIM, B, D_DIM, D_DIM / 64, &LA[0][0], &LB[0][0],
                      acc, tid);
    f16* C = z ? Kh : Q;
#pragma unroll
    for (int mi = 0; mi < 8; ++mi) {
      const size_t xr = ny * 256 + wr * 128 + mi * 16 + ro;
#pragma unroll
      for (int ni = 0; ni < 4; ++ni) {
        f16x4 pk;
#pragma unroll
        for (int rr = 0; rr < 4; ++rr) pk[rr] = (f16)acc[mi][ni][rr];
        *(f16x4*)&C[xr * D_DIM + nx * 256 + wc * 64 + ni * 16 + rq] = pk;
      }
    }
  } else {
    mainloop256<false>(A, D_DIM, B, D_DIM, D_DIM / 64, &LA[0][0], &LB[0][0],
                       acc, tid);
    // unswapped: lane holds 4 consecutive M-rows -> vectorized VT store
#pragma unroll
    for (int mi = 0; mi < 8; ++mi)
#pragma unroll
      for (int ni = 0; ni < 4; ++ni) {
        f16x4 pk;
#pragma unroll
        for (int rr = 0; rr < 4; ++rr) pk[rr] = (f16)acc[mi][ni][rr];
        const size_t d = nx * 256 + wc * 64 + ni * 16 + ro;
        *(f16x4*)&VT[d * N_ROWS + ny * 256 + wr * 128 + mi * 16 + rq] = pk;
      }
  }
}

// ------------------------------------------------ S = exp(QK^T/32 - SHIFT)
// Per-block row sums -> Lpart[row][128] (deterministic, no atomics).
__global__ __launch_bounds__(512, 2) void gemm_s_exp(
    const f16* __restrict__ Q, const f16* __restrict__ Kh, f16* __restrict__ S,
    float* __restrict__ Lpart, int nyb) {
  __shared__ f16 LA[2][16384], LB[2][16384];
  int nx, ny;
  tile2d4(blockIdx.x, nyb, nx, ny);
  const int tid = threadIdx.x, lane = tid & 63;
  const int wr = tid >> 8, wc = (tid >> 6) & 3;
  const int ro = lane & 15, rq = (lane >> 4) * 4;

  f32x4 acc[8][4];
  ACC_INIT8(acc);
  mainloop256<true>(Q + (size_t)ny * 256 * D_DIM, D_DIM,
                    Kh + (size_t)nx * 256 * D_DIM, D_DIM, D_DIM / 64,
                    &LA[0][0], &LB[0][0], acc, tid);

  const float sc = 0.03125f;  // 1/sqrt(1024)
#pragma unroll
  for (int mi = 0; mi < 8; ++mi) {
    const size_t q = ny * 256 + wr * 128 + mi * 16 + ro;
    f16* srow = S + q * N_ROWS + nx * 256 + wc * 64 + rq;
    float rs = 0.f;
#pragma unroll
    for (int ni = 0; ni < 4; ++ni) {
      f16x4 pk;
#pragma unroll
      for (int rr = 0; rr < 4; ++rr) {
        const float p = __expf(acc[mi][ni][rr] * sc - SM_SHIFT);
        rs += p;
        pk[rr] = (f16)p;
      }
      *(f16x4*)&srow[ni * 16] = pk;
    }
    rs += __shfl_xor(rs, 16, 64);
    rs += __shfl_xor(rs, 32, 64);
    if (lane < 16) Lpart[q * 128 + nx * 4 + wc] = rs;
  }
}

// ---------------------------------------------------------------- reduce l
__global__ __launch_bounds__(256) void reduce_l(const float* __restrict__ Lpart,
                                                float* __restrict__ linv,
                                                int rows) {
  const int w = (blockIdx.x * 256 + threadIdx.x) >> 6;  // one wave per row
  const int lane = threadIdx.x & 63;
  if (w >= rows) return;
  const float* p = Lpart + (size_t)w * 128;
  float s = p[lane] + p[lane + 64];
#pragma unroll
  for (int o = 32; o > 0; o >>= 1) s += __shfl_xor(s, o, 64);
  if (lane == 0) linv[w] = 1.0f / s;
}

// ---------------------------------------------------------------- PV
__global__ __launch_bounds__(512, 2) void gemm_pv(const f16* __restrict__ S,
                                                  const f16* __restrict__ VT,
                                                  float* __restrict__ Ppart,
                                                  int nyb, int KS, int chunk) {
  __shared__ f16 LA[2][16384], LB[2][16384];
  const int nid = xcd_swz(blockIdx.x, (int)gridDim.x);
  const int nx = nid & 3, ny = (nid >> 2) % nyb, z = (nid >> 2) / nyb;
  const int tid = threadIdx.x, lane = tid & 63;
  const int wr = tid >> 8, wc = (tid >> 6) & 3;
  const int ro = lane & 15, rq = (lane >> 4) * 4;

  f32x4 acc[8][4];
  ACC_INIT8(acc);
  mainloop256<true>(S + (size_t)ny * 256 * N_ROWS + (size_t)z * KS, N_ROWS,
                    VT + (size_t)nx * 256 * N_ROWS + (size_t)z * KS, N_ROWS,
                    KS / 64, &LA[0][0], &LB[0][0], acc, tid);

  float* out = Ppart + (size_t)z * chunk * D_DIM;
#pragma unroll
  for (int mi = 0; mi < 8; ++mi) {
    const size_t q = ny * 256 + wr * 128 + mi * 16 + ro;
#pragma unroll
    for (int ni = 0; ni < 4; ++ni)
      *(f32x4*)&out[q * D_DIM + nx * 256 + wc * 64 + ni * 16 + rq] =
          acc[mi][ni];
  }
}

// ---------------------------------------------------------------- reduce O
__global__ __launch_bounds__(256) void reduce_o(
    const float* __restrict__ Ppart, const float* __restrict__ linv,
    float* __restrict__ O, int rows, int sk) {
  const int n4 = rows * 256;  // float4 count (rows * 1024 / 4)
  const int stride = gridDim.x * blockDim.x;
  for (int i = blockIdx.x * 256 + threadIdx.x; i < n4; i += stride) {
    f32x4 s = ((const f32x4*)Ppart)[i];
    for (int t = 1; t < sk; ++t) s += ((const f32x4*)Ppart)[(size_t)t * n4 + i];
    const float il = linv[i >> 8];  // row = i*4/1024
    ((f32x4*)O)[i] = s * il;
  }
}

// ---------------------------------------------------------------- launch
extern "C" void kernel_launch(void* const* d_in, const int* in_sizes, int n_in,
                              void* d_out, int out_size, void* d_ws,
                              size_t ws_size, hipStream_t stream) {
  (void)in_sizes;
  (void)n_in;
  (void)out_size;
  const float* X = (const float*)d_in[0];
  const float* WQ = (const float*)d_in[1];
  const float* WK = (const float*)d_in[2];
  const float* WV = (const float*)d_in[3];
  float* O = (float*)d_out;

  // ---- workspace sizing: partials overlay the (dead-after-QKV) Xh/WT region
  const size_t fixedA = (size_t)N_ROWS * D_DIM * 2 + 3ull * D_DIM * D_DIM * 2;
  int chunk = 1024, sk = 1;
  const int pref[][2] = {{8192, 2}, {4096, 2}, {2048, 2}, {8192, 1},
                         {4096, 1}, {2048, 1}, {1024, 1}};
  for (int i = 0; i < 7; ++i) {
    const int c = pref[i][0], s = pref[i][1];
    size_t R = (size_t)s * c * D_DIM * 4;
    if (R < fixedA) R = fixedA;
    const size_t need = R + 3ull * N_ROWS * D_DIM * 2 + (size_t)c * N_ROWS * 2 +
                        (size_t)c * 128 * 4 + (size_t)c * 4 + 4096;
    if (need <= ws_size) {
      chunk = c;
      sk = s;
      break;
    }
  }

  char* base = (char*)d_ws;
  f16* Xh = (f16*)base;
  f16* WT = (f16*)(base + (size_t)N_ROWS * D_DIM * 2);
  float* Ppart = (float*)base;  // overlays Xh/WT (dead after QKV GEMMs)
  size_t R = (size_t)sk * chunk * D_DIM * 4;
  if (R < fixedA) R = fixedA;
  char* p = base + ((R + 255) & ~(size_t)255);
  f16* Q = (f16*)p;
  p += (size_t)N_ROWS * D_DIM * 2;
  f16* Kh = (f16*)p;
  p += (size_t)N_ROWS * D_DIM * 2;
  f16* VT = (f16*)p;
  p += (size_t)N_ROWS * D_DIM * 2;
  f16* S = (f16*)p;
  p += (size_t)chunk * N_ROWS * 2;
  float* Lpart = (float*)p;
  p += (size_t)chunk * 128 * 4;
  float* linv = (float*)p;

  f32_to_f16_kernel<<<2048, 256, 0, stream>>>(X, Xh, N_ROWS * D_DIM / 4);
  transpose_w_kernel<<<dim3(16, 16, 3), 256, 0, stream>>>(WQ, WK, WV, WT);
  gemm_qkv<<<384, 512, 0, stream>>>(Xh, WT, Q, Kh, VT);

  const int KS = N_ROWS / sk;
  for (int mc = 0; mc < N_ROWS; mc += chunk) {
    const int nyb = chunk / 256;
    gemm_s_exp<<<32 * nyb, 512, 0, stream>>>(Q + (size_t)mc * D_DIM, Kh, S,
                                             Lpart, nyb);
    reduce_l<<<(chunk + 3) / 4, 256, 0, stream>>>(Lpart, linv, chunk);
    gemm_pv<<<4 * nyb * sk, 512, 0, stream>>>(S, VT, Ppart, nyb, KS, chunk);
    reduce_o<<<1024, 256, 0, stream>>>(Ppart, linv, O + (size_t)mc * D_DIM,
                                       chunk, sk);
  }
}

// Round 7
// 392.921 us; speedup vs baseline: 1.4080x; 1.0257x over previous
//
#include <hip/hip_runtime.h>

#define N_ROWS 8192
#define D_DIM  1024
#define SM_SHIFT 4.0f

typedef _Float16 f16;
typedef _Float16 f16x8 __attribute__((ext_vector_type(8)));
typedef _Float16 f16x4 __attribute__((ext_vector_type(4)));
typedef float    f32x4 __attribute__((ext_vector_type(4)));

// offset=0 form only — the exact intrinsic usage verified in rounds 1-3,5,6.
__device__ __forceinline__ void gload16(const void* g, void* l) {
  __builtin_amdgcn_global_load_lds(
      (const __attribute__((address_space(1))) void*)g,
      (__attribute__((address_space(3))) void*)l, 16, 0, 0);
}

// XCD-chunked swizzle (m157): consecutive virtual ids land on one XCD.
__device__ __forceinline__ int xcd_swz(int bid, int nb) {
  return (bid & 7) * (nb >> 3) + (bid >> 3);
}

// 4x4 supertile of 256^2 tiles per co-XCD chunk: 4 A-panels + 4 B-panels
// (256x1024x2B = 512KB each) = 4MB = one XCD L2. Requires ny_t % 4 == 0.
__device__ __forceinline__ void tile2d4(int bid, int ny_t, int& nx, int& ny) {
  const int v = xcd_swz(bid, 32 * ny_t);
  const int g = v >> 4, w = v & 15;
  const int gpc = ny_t >> 2;
  const int gx = g / gpc, gy = g - gx * gpc;
  nx = gx * 4 + (w & 3);
  ny = gy * 4 + (w >> 2);
}

// ---------------------------------------------------------------- converts
__global__ __launch_bounds__(256) void f32_to_f16_kernel(
    const float* __restrict__ in, f16* __restrict__ out, int n4) {
  for (int i = blockIdx.x * blockDim.x + threadIdx.x; i < n4;
       i += gridDim.x * blockDim.x) {
    float4 x = ((const float4*)in)[i];
    f16x4 h = {(f16)x.x, (f16)x.y, (f16)x.z, (f16)x.w};
    ((f16x4*)out)[i] = h;
  }
}

__global__ __launch_bounds__(256) void transpose_w_kernel(
    const float* __restrict__ w0, const float* __restrict__ w1,
    const float* __restrict__ w2, f16* __restrict__ WT) {
  const float* W = (blockIdx.z == 0) ? w0 : (blockIdx.z == 1) ? w1 : w2;
  f16* T = WT + (size_t)blockIdx.z * D_DIM * D_DIM;
  __shared__ float tile[64][65];
  const int r0 = blockIdx.y * 64, c0 = blockIdx.x * 64;
  const int t = threadIdx.x;
#pragma unroll
  for (int rep = 0; rep < 16; ++rep) {
    int idx = rep * 256 + t;
    int r = idx >> 6, c = idx & 63;
    tile[r][c] = W[(size_t)(r0 + r) * D_DIM + (c0 + c)];
  }
  __syncthreads();
#pragma unroll
  for (int rep = 0; rep < 16; ++rep) {
    int idx = rep * 256 + t;
    int r = idx >> 6, c = idx & 63;
    T[(size_t)(c0 + r) * D_DIM + (r0 + c)] = (f16)tile[c][r];
  }
}

// --------------------------------------------- 256^2 BK=64 swizzled mainloop
// Identical sync structure + LDS swizzle to round 6 (verified: 0 bank
// conflicts, passed). NEW: within-K-step fragment-read pipelining — issue
// h0's 12 reads + h1's 8 A-reads upfront, lgkmcnt(8) -> h0 MFMA cluster
// (h1-A reads complete underneath) -> issue h1's 4 B-reads -> lgkmcnt(0) ->
// h1 MFMA. Cuts the exposed LDS wait from 2 full batches to 1 first batch.
template <bool SWAP>
__device__ __forceinline__ void mainloop256(const f16* __restrict__ Ag, int lda,
                                            const f16* __restrict__ Bg,
                                            int ldbt, int nk, f16* LA, f16* LB,
                                            f32x4 (&acc)[8][4], int tid) {
  const int lane = tid & 63;
  const int wr = tid >> 8, wc = (tid >> 6) & 3;
  const int ro = lane & 15;
  const int jj0 = (((lane >> 4) ^ (ro & 7)) << 4);  // swizzled 16B col, h=0
  const int rs = tid >> 3;                          // staging row (0..63)
  const int ce = ((tid & 7) ^ (rs & 7)) * 8;        // pre-swizzled src col
  const f16* a[4];
  const f16* b[4];
#pragma unroll
  for (int s = 0; s < 4; ++s) {
    a[s] = Ag + (size_t)(rs + 64 * s) * lda + ce;
    b[s] = Bg + (size_t)(rs + 64 * s) * ldbt + ce;
  }
  char* la = (char*)LA;
  char* lb = (char*)LB;
  const int t16 = tid * 16;

  // stage next K64-tile (A 32KB + B 32KB, 8 loads) into buffer buf
  auto stage = [&](int buf) {
    char* A = la + buf * 32768;
    char* B = lb + buf * 32768;
#pragma unroll
    for (int s = 0; s < 4; ++s) {
      gload16(a[s], A + s * 8192 + t16);
      gload16(b[s], B + s * 8192 + t16);
    }
#pragma unroll
    for (int s = 0; s < 4; ++s) {
      a[s] += 64;
      b[s] += 64;
    }
  };

  stage(0);

  for (int kt = 0; kt < nk; ++kt) {
    const int buf = kt & 1;
    if (kt + 1 < nk) {
      stage(buf ^ 1);  // 8 newest loads stay in flight across the barrier
      asm volatile("s_waitcnt vmcnt(8)" ::: "memory");  // tile kt landed
    } else {
      asm volatile("s_waitcnt vmcnt(0)" ::: "memory");
    }
    __builtin_amdgcn_s_barrier();  // #1: tile kt visible to all waves
    __builtin_amdgcn_sched_barrier(0);
    const char* ab = la + buf * 32768;
    const char* bb = lb + buf * 32768;
    const int jo0 = jj0;       // k-slots 0..3
    const int jo1 = jj0 ^ 64;  // k-slots 4..7 (XOR preserves the swizzle)
    f16x8 af0[8], bf0[4], af1[8], bf1[4];
#pragma unroll
    for (int mi = 0; mi < 8; ++mi)
      af0[mi] = *(const f16x8*)(ab + (wr * 128 + mi * 16 + ro) * 128 + jo0);
#pragma unroll
    for (int ni = 0; ni < 4; ++ni)
      bf0[ni] = *(const f16x8*)(bb + (wc * 64 + ni * 16 + ro) * 128 + jo0);
#pragma unroll
    for (int mi = 0; mi < 8; ++mi)  // h1 A-fragments prefetched (in flight)
      af1[mi] = *(const f16x8*)(ab + (wr * 128 + mi * 16 + ro) * 128 + jo1);
    asm volatile("s_waitcnt lgkmcnt(8)" ::: "memory");  // h0's 12 ready
    __builtin_amdgcn_sched_barrier(0);  // rule #18: pin MFMA below the wait
    __builtin_amdgcn_s_setprio(1);
#pragma unroll
    for (int mi = 0; mi < 8; ++mi)
#pragma unroll
      for (int ni = 0; ni < 4; ++ni)
        acc[mi][ni] =
            SWAP ? __builtin_amdgcn_mfma_f32_16x16x32_f16(bf0[ni], af0[mi],
                                                          acc[mi][ni], 0, 0, 0)
                 : __builtin_amdgcn_mfma_f32_16x16x32_f16(af0[mi], bf0[ni],
                                                          acc[mi][ni], 0, 0, 0);
    __builtin_amdgcn_s_setprio(0);
#pragma unroll
    for (int ni = 0; ni < 4; ++ni)
      bf1[ni] = *(const f16x8*)(bb + (wc * 64 + ni * 16 + ro) * 128 + jo1);
    asm volatile("s_waitcnt lgkmcnt(0)" ::: "memory");
    __builtin_amdgcn_sched_barrier(0);
    __builtin_amdgcn_s_setprio(1);
#pragma unroll
    for (int mi = 0; mi < 8; ++mi)
#pragma unroll
      for (int ni = 0; ni < 4; ++ni)
        acc[mi][ni] =
            SWAP ? __builtin_amdgcn_mfma_f32_16x16x32_f16(bf1[ni], af1[mi],
                                                          acc[mi][ni], 0, 0, 0)
                 : __builtin_amdgcn_mfma_f32_16x16x32_f16(af1[mi], bf1[ni],
                                                          acc[mi][ni], 0, 0, 0);
    __builtin_amdgcn_s_setprio(0);
    __builtin_amdgcn_s_barrier();  // #2: all reads of buf done -> restage safe
  }
}

#define ACC_INIT8(acc)                                \
  _Pragma("unroll") for (int i = 0; i < 8; ++i)       \
      _Pragma("unroll") for (int j = 0; j < 4; ++j)   \
          acc[i][j] = (f32x4){0.f, 0.f, 0.f, 0.f};

// ---------------------------------------------------------------- QKV GEMM
__global__ __launch_bounds__(512, 2) void gemm_qkv(
    const f16* __restrict__ Xh, const f16* __restrict__ WT,
    f16* __restrict__ Q, f16* __restrict__ Kh, f16* __restrict__ VT) {
  __shared__ f16 LA[2][16384], LB[2][16384];
  const int v = xcd_swz(blockIdx.x, 384);
  const int z = v >> 7, r = v & 127;
  const int nx = r & 3, ny = r >> 2;
  const int tid = threadIdx.x, lane = tid & 63;
  const int wr = tid >> 8, wc = (tid >> 6) & 3;
  const int ro = lane & 15, rq = (lane >> 4) * 4;

  const f16* A = Xh + (size_t)ny * 256 * D_DIM;
  const f16* B = WT + (size_t)z * D_DIM * D_DIM + (size_t)nx * 256 * D_DIM;

  f32x4 acc[8][4];
  ACC_INIT8(acc);
  if (z < 2) {
    mainloop256<true>(A, D_DIM, B, D_DIM, D_DIM / 64, &LA[0][0], &LB[0][0],
                      acc, tid);
    f16* C = z ? Kh : Q;
#pragma unroll
    for (int mi = 0; mi < 8; ++mi) {
      const size_t xr = ny * 256 + wr * 128 + mi * 16 + ro;
#pragma unroll
      for (int ni = 0; ni < 4; ++ni) {
        f16x4 pk;
#pragma unroll
        for (int rr = 0; rr < 4; ++rr) pk[rr] = (f16)acc[mi][ni][rr];
        *(f16x4*)&C[xr * D_DIM + nx * 256 + wc * 64 + ni * 16 + rq] = pk;
      }
    }
  } else {
    mainloop256<false>(A, D_DIM, B, D_DIM, D_DIM / 64, &LA[0][0], &LB[0][0],
                       acc, tid);
    // unswapped: lane holds 4 consecutive M-rows -> vectorized VT store
#pragma unroll
    for (int mi = 0; mi < 8; ++mi)
#pragma unroll
      for (int ni = 0; ni < 4; ++ni) {
        f16x4 pk;
#pragma unroll
        for (int rr = 0; rr < 4; ++rr) pk[rr] = (f16)acc[mi][ni][rr];
        const size_t d = nx * 256 + wc * 64 + ni * 16 + ro;
        *(f16x4*)&VT[d * N_ROWS + ny * 256 + wr * 128 + mi * 16 + rq] = pk;
      }
  }
}

// ------------------------------------------------ S = exp(QK^T/32 - SHIFT)
// Per-block row sums -> Lpart[row][128] (deterministic, no atomics).
__global__ __launch_bounds__(512, 2) void gemm_s_exp(
    const f16* __restrict__ Q, const f16* __restrict__ Kh, f16* __restrict__ S,
    float* __restrict__ Lpart, int nyb) {
  __shared__ f16 LA[2][16384], LB[2][16384];
  int nx, ny;
  tile2d4(blockIdx.x, nyb, nx, ny);
  const int tid = threadIdx.x, lane = tid & 63;
  const int wr = tid >> 8, wc = (tid >> 6) & 3;
  const int ro = lane & 15, rq = (lane >> 4) * 4;

  f32x4 acc[8][4];
  ACC_INIT8(acc);
  mainloop256<true>(Q + (size_t)ny * 256 * D_DIM, D_DIM,
                    Kh + (size_t)nx * 256 * D_DIM, D_DIM, D_DIM / 64,
                    &LA[0][0], &LB[0][0], acc, tid);

  const float sc = 0.03125f;  // 1/sqrt(1024)
#pragma unroll
  for (int mi = 0; mi < 8; ++mi) {
    const size_t q = ny * 256 + wr * 128 + mi * 16 + ro;
    f16* srow = S + q * N_ROWS + nx * 256 + wc * 64 + rq;
    float rs = 0.f;
#pragma unroll
    for (int ni = 0; ni < 4; ++ni) {
      f16x4 pk;
#pragma unroll
      for (int rr = 0; rr < 4; ++rr) {
        const float p = __expf(acc[mi][ni][rr] * sc - SM_SHIFT);
        rs += p;
        pk[rr] = (f16)p;
      }
      *(f16x4*)&srow[ni * 16] = pk;
    }
    rs += __shfl_xor(rs, 16, 64);
    rs += __shfl_xor(rs, 32, 64);
    if (lane < 16) Lpart[q * 128 + nx * 4 + wc] = rs;
  }
}

// ---------------------------------------------------------------- reduce l
__global__ __launch_bounds__(256) void reduce_l(const float* __restrict__ Lpart,
                                                float* __restrict__ linv,
                                                int rows) {
  const int w = (blockIdx.x * 256 + threadIdx.x) >> 6;  // one wave per row
  const int lane = threadIdx.x & 63;
  if (w >= rows) return;
  const float* p = Lpart + (size_t)w * 128;
  float s = p[lane] + p[lane + 64];
#pragma unroll
  for (int o = 32; o > 0; o >>= 1) s += __shfl_xor(s, o, 64);
  if (lane == 0) linv[w] = 1.0f / s;
}

// ---------------------------------------------------------------- PV
__global__ __launch_bounds__(512, 2) void gemm_pv(const f16* __restrict__ S,
                                                  const f16* __restrict__ VT,
                                                  float* __restrict__ Ppart,
                                                  int nyb, int KS, int chunk) {
  __shared__ f16 LA[2][16384], LB[2][16384];
  const int nid = xcd_swz(blockIdx.x, (int)gridDim.x);
  const int nx = nid & 3, ny = (nid >> 2) % nyb, z = (nid >> 2) / nyb;
  const int tid = threadIdx.x, lane = tid & 63;
  const int wr = tid >> 8, wc = (tid >> 6) & 3;
  const int ro = lane & 15, rq = (lane >> 4) * 4;

  f32x4 acc[8][4];
  ACC_INIT8(acc);
  mainloop256<true>(S + (size_t)ny * 256 * N_ROWS + (size_t)z * KS, N_ROWS,
                    VT + (size_t)nx * 256 * N_ROWS + (size_t)z * KS, N_ROWS,
                    KS / 64, &LA[0][0], &LB[0][0], acc, tid);

  float* out = Ppart + (size_t)z * chunk * D_DIM;
#pragma unroll
  for (int mi = 0; mi < 8; ++mi) {
    const size_t q = ny * 256 + wr * 128 + mi * 16 + ro;
#pragma unroll
    for (int ni = 0; ni < 4; ++ni)
      *(f32x4*)&out[q * D_DIM + nx * 256 + wc * 64 + ni * 16 + rq] =
          acc[mi][ni];
  }
}

// ---------------------------------------------------------------- reduce O
__global__ __launch_bounds__(256) void reduce_o(
    const float* __restrict__ Ppart, const float* __restrict__ linv,
    float* __restrict__ O, int rows, int sk) {
  const int n4 = rows * 256;  // float4 count (rows * 1024 / 4)
  const int stride = gridDim.x * blockDim.x;
  for (int i = blockIdx.x * 256 + threadIdx.x; i < n4; i += stride) {
    f32x4 s = ((const f32x4*)Ppart)[i];
    for (int t = 1; t < sk; ++t) s += ((const f32x4*)Ppart)[(size_t)t * n4 + i];
    const float il = linv[i >> 8];  // row = i*4/1024
    ((f32x4*)O)[i] = s * il;
  }
}

// ---------------------------------------------------------------- launch
extern "C" void kernel_launch(void* const* d_in, const int* in_sizes, int n_in,
                              void* d_out, int out_size, void* d_ws,
                              size_t ws_size, hipStream_t stream) {
  (void)in_sizes;
  (void)n_in;
  (void)out_size;
  const float* X = (const float*)d_in[0];
  const float* WQ = (const float*)d_in[1];
  const float* WK = (const float*)d_in[2];
  const float* WV = (const float*)d_in[3];
  float* O = (float*)d_out;

  // ---- workspace sizing: partials overlay the (dead-after-QKV) Xh/WT region
  const size_t fixedA = (size_t)N_ROWS * D_DIM * 2 + 3ull * D_DIM * D_DIM * 2;
  int chunk = 1024, sk = 1;
  const int pref[][2] = {{8192, 2}, {4096, 2}, {2048, 2}, {8192, 1},
                         {4096, 1}, {2048, 1}, {1024, 1}};
  for (int i = 0; i < 7; ++i) {
    const int c = pref[i][0], s = pref[i][1];
    size_t R = (size_t)s * c * D_DIM * 4;
    if (R < fixedA) R = fixedA;
    const size_t need = R + 3ull * N_ROWS * D_DIM * 2 + (size_t)c * N_ROWS * 2 +
                        (size_t)c * 128 * 4 + (size_t)c * 4 + 4096;
    if (need <= ws_size) {
      chunk = c;
      sk = s;
      break;
    }
  }

  char* base = (char*)d_ws;
  f16* Xh = (f16*)base;
  f16* WT = (f16*)(base + (size_t)N_ROWS * D_DIM * 2);
  float* Ppart = (float*)base;  // overlays Xh/WT (dead after QKV GEMMs)
  size_t R = (size_t)sk * chunk * D_DIM * 4;
  if (R < fixedA) R = fixedA;
  char* p = base + ((R + 255) & ~(size_t)255);
  f16* Q = (f16*)p;
  p += (size_t)N_ROWS * D_DIM * 2;
  f16* Kh = (f16*)p;
  p += (size_t)N_ROWS * D_DIM * 2;
  f16* VT = (f16*)p;
  p += (size_t)N_ROWS * D_DIM * 2;
  f16* S = (f16*)p;
  p += (size_t)chunk * N_ROWS * 2;
  float* Lpart = (float*)p;
  p += (size_t)chunk * 128 * 4;
  float* linv = (float*)p;

  f32_to_f16_kernel<<<2048, 256, 0, stream>>>(X, Xh, N_ROWS * D_DIM / 4);
  transpose_w_kernel<<<dim3(16, 16, 3), 256, 0, stream>>>(WQ, WK, WV, WT);
  gemm_qkv<<<384, 512, 0, stream>>>(Xh, WT, Q, Kh, VT);

  const int KS = N_ROWS / sk;
  for (int mc = 0; mc < N_ROWS; mc += chunk) {
    const int nyb = chunk / 256;
    gemm_s_exp<<<32 * nyb, 512, 0, stream>>>(Q + (size_t)mc * D_DIM, Kh, S,
                                             Lpart, nyb);
    reduce_l<<<(chunk + 3) / 4, 256, 0, stream>>>(Lpart, linv, chunk);
    gemm_pv<<<4 * nyb * sk, 512, 0, stream>>>(S, VT, Ppart, nyb, KS, chunk);
    reduce_o<<<1024, 256, 0, stream>>>(Ppart, linv, O + (size_t)mc * D_DIM,
                                       chunk, sk);
  }
}